// Round 1
// baseline (519.062 us; speedup 1.0000x reference)
//
#include <hip/hip_runtime.h>
#include <hip/hip_bf16.h>
#include <stdint.h>

#define DEV __device__ __forceinline__

typedef unsigned short u16;
typedef unsigned int   u32;
typedef __attribute__((ext_vector_type(8))) short bf16x8;   // 8 bf16 = 4 VGPRs
typedef __attribute__((ext_vector_type(4))) float f32x4;
typedef __attribute__((ext_vector_type(4))) u32   u32x4;
typedef __attribute__((ext_vector_type(2))) u32   u32x2;

// ---- numeric helpers -------------------------------------------------------
DEV u16 f2bf(float f) {            // RNE f32 -> bf16
  u32 u = __builtin_bit_cast(u32, f);
  u = (u + 0x7fffu + ((u >> 16) & 1u)) >> 16;
  return (u16)u;
}
DEV float bf2f(u16 h) { return __builtin_bit_cast(float, (u32)h << 16); }
DEV u32 pk2(float a, float b) {    // pack 2 f32 -> 2 bf16 in one u32 (RNE)
  u32 x = __builtin_bit_cast(u32, a), y = __builtin_bit_cast(u32, b);
  x = (x + 0x7fffu + ((x >> 16) & 1u)) >> 16;
  y = (y + 0x7fffu + ((y >> 16) & 1u)) >> 16;
  return x | (y << 16);
}
DEV f32x4 mfma16(bf16x8 a, bf16x8 b, f32x4 c) {
  return __builtin_amdgcn_mfma_f32_16x16x32_bf16(a, b, c, 0, 0, 0);
}

// ---- problem constants -----------------------------------------------------
// B=2 T=2048 DIM=1024 HEADS=16 HEAD_DIM=64; tokens = 4096
// workspace layout (bytes):
//  XB      0         x as bf16            [4096][1024]
//  WQKVT   8388608   Wqkv^T bf16          [3072][1024]
//  WPROJT  14680064  Wproj^T bf16         [1024][1024]
//  QKV     16777216  qkv bf16             [4096][3072]
//  QR      41943040  roped*scale Q bf16   [32][2048][64]
//  KR      50331648  roped K bf16         [32][2048][64]
//  VT      58720256  V^T bf16             [32][64][2048]
//  AO      67108864  attn out bf16        [4096][1024]
//  SIN     75497472  f32 [2048][32]
//  COS     75759616  f32 [2048][32]

// ---- prep kernels ----------------------------------------------------------
__global__ __launch_bounds__(256) void k_cvt_bf16(const float* __restrict__ in,
                                                  u16* __restrict__ out) {
  size_t i = ((size_t)blockIdx.x * 256 + threadIdx.x) * 8;
  float4 a = *(const float4*)(in + i);
  float4 b = *(const float4*)(in + i + 4);
  u32x4 o = { pk2(a.x, a.y), pk2(a.z, a.w), pk2(b.x, b.y), pk2(b.z, b.w) };
  *(u32x4*)(out + i) = o;
}

// W [1024][Ndim] f32 -> WT [Ndim][1024] bf16 (coalesced both sides via LDS)
__global__ __launch_bounds__(256) void k_transpose_cvt(const float* __restrict__ W,
                                                       u16* __restrict__ WT,
                                                       int Ndim) {
  int bk = blockIdx.x & 31;        // K/32 = 32
  int bn = blockIdx.x >> 5;
  int k0 = bk * 32, n0 = bn * 32;
  __shared__ float t[32][33];
  int tx = threadIdx.x & 31, ty = threadIdx.x >> 5; // ty 0..7
#pragma unroll
  for (int i = 0; i < 4; ++i)
    t[ty + 8 * i][tx] = W[(size_t)(k0 + ty + 8 * i) * Ndim + n0 + tx];
  __syncthreads();
#pragma unroll
  for (int i = 0; i < 4; ++i) {
    int n = ty + 8 * i;
    WT[(size_t)(n0 + n) * 1024 + k0 + tx] = f2bf(t[tx][n]);
  }
}

__global__ __launch_bounds__(256) void k_tables(const int* __restrict__ posp,
                                                float* __restrict__ sint,
                                                float* __restrict__ cost) {
  int i = blockIdx.x * 256 + threadIdx.x;   // 65536 = 2048*32
  int t = i >> 5, d = i & 31;
  // theta = 10000^(-d/32) = 2^(-d/32 * log2(10000))
  float theta = exp2f(-(float)d * (13.2877123795494f / 32.0f));
  float ang = (float)(posp[0] + t) * theta;
  sint[i] = sinf(ang);
  cost[i] = cosf(ang);
}

// ---- GEMM: C[4096][N] = A[4096][1024] @ BT^T + bias ------------------------
// 128x128 tile, BK=32, 4 waves (2x2 of 64x64), mfma 16x16x32 bf16.
// LDS chunk-swizzle c^((r>>1)&3): 2-way max bank aliasing on ds_read_b128.
template <int N, bool OUTF32>
__global__ __launch_bounds__(256) void k_gemm(const u16* __restrict__ A,
                                              const u16* __restrict__ BT,
                                              const float* __restrict__ bias,
                                              void* __restrict__ Cout) {
  constexpr int K = 1024;
  int bm = blockIdx.x & 31;             // M/128 = 32
  int bn = blockIdx.x >> 5;
  int m0 = bm * 128, n0 = bn * 128;
  int tid = threadIdx.x, lane = tid & 63, w = tid >> 6;
  int g = lane >> 4, l15 = lane & 15;
  int wr = w >> 1, wc = w & 1;

  __shared__ u16 Alds[128 * 32];
  __shared__ u16 Blds[128 * 32];

  f32x4 acc[4][4] = {};

  int r_st = tid >> 2;                  // staging row within 64-row half
  int c_st = tid & 3;                   // staging 16B chunk

  uint4 va[2], vb[2];
#pragma unroll
  for (int rd = 0; rd < 2; ++rd) {
    int r = rd * 64 + r_st;
    va[rd] = *(const uint4*)(A  + (size_t)(m0 + r) * K + c_st * 8);
    vb[rd] = *(const uint4*)(BT + (size_t)(n0 + r) * K + c_st * 8);
  }

  for (int k0 = 0; k0 < K; k0 += 32) {
#pragma unroll
    for (int rd = 0; rd < 2; ++rd) {
      int r = rd * 64 + r_st;
      int dst = r * 64 + ((c_st ^ ((r >> 1) & 3)) << 4);
      *(uint4*)((char*)Alds + dst) = va[rd];
      *(uint4*)((char*)Blds + dst) = vb[rd];
    }
    __syncthreads();
    if (k0 + 32 < K) {                  // prefetch next K-step under MFMA
#pragma unroll
      for (int rd = 0; rd < 2; ++rd) {
        int r = rd * 64 + r_st;
        va[rd] = *(const uint4*)(A  + (size_t)(m0 + r) * K + k0 + 32 + c_st * 8);
        vb[rd] = *(const uint4*)(BT + (size_t)(n0 + r) * K + k0 + 32 + c_st * 8);
      }
    }
    bf16x8 af[4], bf_[4];
#pragma unroll
    for (int m = 0; m < 4; ++m) {
      int r = wr * 64 + m * 16 + l15;
      af[m] = *(const bf16x8*)((const char*)Alds + r * 64 + ((g ^ ((r >> 1) & 3)) << 4));
    }
#pragma unroll
    for (int n = 0; n < 4; ++n) {
      int r = wc * 64 + n * 16 + l15;
      bf_[n] = *(const bf16x8*)((const char*)Blds + r * 64 + ((g ^ ((r >> 1) & 3)) << 4));
    }
#pragma unroll
    for (int m = 0; m < 4; ++m)
#pragma unroll
      for (int n = 0; n < 4; ++n)
        acc[m][n] = mfma16(af[m], bf_[n], acc[m][n]);
    __syncthreads();
  }

  // epilogue: D row = 4*g + j (per 16-block), col = l15
#pragma unroll
  for (int m = 0; m < 4; ++m) {
    int rowb = m0 + wr * 64 + m * 16 + 4 * g;
#pragma unroll
    for (int n = 0; n < 4; ++n) {
      int col = n0 + wc * 64 + n * 16 + l15;
      float bv = bias[col];
#pragma unroll
      for (int j = 0; j < 4; ++j) {
        float v = acc[m][n][j] + bv;
        if constexpr (OUTF32)
          ((float*)Cout)[(size_t)(rowb + j) * N + col] = v;
        else
          ((u16*)Cout)[(size_t)(rowb + j) * N + col] = f2bf(v);
      }
    }
  }
}

// ---- RoPE + head reshape + V transpose -------------------------------------
// qkv [4096][3072] bf16 -> QR/KR [bh][t][64] (Q scaled by 0.125), VT [bh][64][t]
__global__ __launch_bounds__(256) void k_rope(const u16* __restrict__ qkv,
                                              const float* __restrict__ sint,
                                              const float* __restrict__ cost,
                                              u16* __restrict__ QR,
                                              u16* __restrict__ KR,
                                              u16* __restrict__ VT) {
  int bid = blockIdx.x;
  int bh = bid >> 5;                 // T/64 = 32 blocks per (b,h)
  int t0 = (bid & 31) * 64;
  int b = bh >> 4, h = bh & 15;
  int tid = threadIdx.x;

  // part 1: rope on q,k. 64 tokens x 32 pairs.
  int dp = tid & 31;
  int tt0 = tid >> 5;                 // 0..7
#pragma unroll
  for (int r = 0; r < 8; ++r) {
    int tl = r * 8 + tt0;
    int t = t0 + tl;
    int tok = b * 2048 + t;
    const u16* row = qkv + (size_t)tok * 3072;
    float sn = sint[t * 32 + dp], cs = cost[t * 32 + dp];

    u32 qq = *(const u32*)(row + h * 64 + 2 * dp);
    float x1 = bf2f((u16)qq), x2 = bf2f((u16)(qq >> 16));
    u16* qo = QR + ((size_t)bh * 2048 + t) * 64;
    qo[dp]      = f2bf(0.125f * (x1 * cs - x2 * sn));
    qo[dp + 32] = f2bf(0.125f * (x1 * sn + x2 * cs));

    u32 kk = *(const u32*)(row + 1024 + h * 64 + 2 * dp);
    x1 = bf2f((u16)kk); x2 = bf2f((u16)(kk >> 16));
    u16* ko = KR + ((size_t)bh * 2048 + t) * 64;
    ko[dp]      = f2bf(x1 * cs - x2 * sn);
    ko[dp + 32] = f2bf(x1 * sn + x2 * cs);
  }

  // part 2: V transpose via LDS (row stride 72*2=144B, 16B aligned)
  __shared__ u16 vld[64][72];
#pragma unroll
  for (int it = 0; it < 2; ++it) {
    int slot = it * 256 + tid;
    int tl = slot >> 3, ch = slot & 7;
    int tok = b * 2048 + t0 + tl;
    uint4 v = *(const uint4*)(qkv + (size_t)tok * 3072 + 2048 + h * 64 + ch * 8);
    *(uint4*)&vld[tl][ch * 8] = v;
  }
  __syncthreads();
#pragma unroll
  for (int it = 0; it < 2; ++it) {
    int slot = it * 256 + tid;
    int d = slot >> 3, tch = slot & 7;
    u16 tmp[8];
#pragma unroll
    for (int i = 0; i < 8; ++i) tmp[i] = vld[tch * 8 + i][d];
    u32x4 o = { (u32)tmp[0] | ((u32)tmp[1] << 16), (u32)tmp[2] | ((u32)tmp[3] << 16),
                (u32)tmp[4] | ((u32)tmp[5] << 16), (u32)tmp[6] | ((u32)tmp[7] << 16) };
    *(u32x4*)(VT + ((size_t)bh * 64 + d) * 2048 + t0 + tch * 8) = o;
  }
}

// ---- causal flash attention (swapped-operand, per-lane softmax) ------------
// wave = 16 q rows. S^T = mfma(K, Q): lane owns column q = q0+l15.
// PV via k-permuted 16x16x32: B-frag = lane's own packed P values (no shuffles).
__global__ __launch_bounds__(256) void k_attn(const u16* __restrict__ QR,
                                              const u16* __restrict__ KR,
                                              const u16* __restrict__ VT,
                                              u16* __restrict__ AO) {
  int tid = threadIdx.x;
  int w = tid >> 6, lane = tid & 63;
  int g = lane >> 4, l15 = lane & 15;
  int W = blockIdx.x * 4 + w;
  int bh = W >> 7;                   // 128 q-tiles per (b,h)
  int qt = W & 127;
  int q0 = qt * 16;
  int b = bh >> 4, h = bh & 15;
  int q_abs = q0 + l15;

  const u16* Qrow = QR + ((size_t)bh * 2048 + q0 + l15) * 64 + 8 * g;
  bf16x8 qf0 = *(const bf16x8*)(Qrow);
  bf16x8 qf1 = *(const bf16x8*)(Qrow + 32);

  const u16* Kbase = KR + (size_t)bh * 2048 * 64;
  const u16* Vbase = VT + (size_t)bh * 64 * 2048;

  f32x4 oacc[4] = {};                // O^T[d = dblk*16+4g+j][q = l15]
  float m_run = -1e30f, l_run = 0.0f;

  int ntiles = (q0 + 79) >> 6;       // cover tk in [0, ceil((q0+16)/64)*64)
  for (int tI = 0; tI < ntiles; ++tI) {
    int tk0 = tI * 64;
    // S^T for 64 tk x 16 q
    f32x4 sb[4];
#pragma unroll
    for (int blk = 0; blk < 4; ++blk) {
      const u16* krow = Kbase + (size_t)(tk0 + blk * 16 + l15) * 64 + 8 * g;
      f32x4 s = {0.f, 0.f, 0.f, 0.f};
      s = mfma16(*(const bf16x8*)krow, qf0, s);
      s = mfma16(*(const bf16x8*)(krow + 32), qf1, s);
      sb[blk] = s;
    }
    if (tk0 + 63 > q0) {             // causal boundary tile(s)
#pragma unroll
      for (int blk = 0; blk < 4; ++blk)
#pragma unroll
        for (int j = 0; j < 4; ++j) {
          int tk = tk0 + blk * 16 + 4 * g + j;
          if (tk > q_abs) sb[blk][j] = -1e30f;
        }
    }
    // online softmax (per-lane column q; cross-lane over {l, l^16, l^32})
    float mx = -1e30f;
#pragma unroll
    for (int blk = 0; blk < 4; ++blk)
#pragma unroll
      for (int j = 0; j < 4; ++j) mx = fmaxf(mx, sb[blk][j]);
    mx = fmaxf(mx, __shfl_xor(mx, 16));
    mx = fmaxf(mx, __shfl_xor(mx, 32));
    float mnew = fmaxf(m_run, mx);
    float alpha = exp2f((m_run - mnew) * 1.44269504f);
    float p[4][4];
    float psum = 0.f;
#pragma unroll
    for (int blk = 0; blk < 4; ++blk)
#pragma unroll
      for (int j = 0; j < 4; ++j) {
        float pv = exp2f((sb[blk][j] - mnew) * 1.44269504f);
        p[blk][j] = pv;
        psum += pv;
      }
    psum += __shfl_xor(psum, 16);
    psum += __shfl_xor(psum, 32);
    l_run = l_run * alpha + psum;
    m_run = mnew;
#pragma unroll
    for (int dblk = 0; dblk < 4; ++dblk) oacc[dblk] *= alpha;

    // PV: O^T += V^T · P^T, K-dim permuted so B-frag is lane-local
#pragma unroll
    for (int s2 = 0; s2 < 2; ++s2) {
      u32x4 pu = { pk2(p[2 * s2][0], p[2 * s2][1]),
                   pk2(p[2 * s2][2], p[2 * s2][3]),
                   pk2(p[2 * s2 + 1][0], p[2 * s2 + 1][1]),
                   pk2(p[2 * s2 + 1][2], p[2 * s2 + 1][3]) };
      bf16x8 pb = __builtin_bit_cast(bf16x8, pu);
#pragma unroll
      for (int dblk = 0; dblk < 4; ++dblk) {
        const u16* vrow = Vbase + (size_t)(dblk * 16 + l15) * 2048 + tk0 + 32 * s2 + 4 * g;
        uint2 lo = *(const uint2*)vrow;          // tk = 32*s2 + 4g + 0..3
        uint2 hi = *(const uint2*)(vrow + 16);   // tk = 32*s2 + 16 + 4g + 0..3
        u32x4 vv = { lo.x, lo.y, hi.x, hi.y };
        bf16x8 va = __builtin_bit_cast(bf16x8, vv);
        oacc[dblk] = mfma16(va, pb, oacc[dblk]);
      }
    }
  }

  float inv = 1.0f / l_run;
  u16* orow = AO + ((size_t)b * 2048 + q0 + l15) * 1024 + h * 64 + 4 * g;
#pragma unroll
  for (int dblk = 0; dblk < 4; ++dblk) {
    u32x2 o = { pk2(oacc[dblk][0] * inv, oacc[dblk][1] * inv),
                pk2(oacc[dblk][2] * inv, oacc[dblk][3] * inv) };
    *(u32x2*)(orow + dblk * 16) = o;
  }
}

// ---- launcher ---------------------------------------------------------------
extern "C" void kernel_launch(void* const* d_in, const int* in_sizes, int n_in,
                              void* d_out, int out_size, void* d_ws, size_t ws_size,
                              hipStream_t stream) {
  (void)in_sizes; (void)n_in; (void)out_size; (void)ws_size;
  const float* x     = (const float*)d_in[0];
  const float* Wqkv  = (const float*)d_in[1];
  const float* bqkv  = (const float*)d_in[2];
  const float* Wproj = (const float*)d_in[3];
  const float* bproj = (const float*)d_in[4];
  const int*   pos   = (const int*)d_in[5];

  char* ws = (char*)d_ws;
  u16*   XB     = (u16*)(ws + 0);
  u16*   WQKVT  = (u16*)(ws + 8388608);
  u16*   WPROJT = (u16*)(ws + 14680064);
  u16*   QKV    = (u16*)(ws + 16777216);
  u16*   QR     = (u16*)(ws + 41943040);
  u16*   KR     = (u16*)(ws + 50331648);
  u16*   VT     = (u16*)(ws + 58720256);
  u16*   AO     = (u16*)(ws + 67108864);
  float* SIN    = (float*)(ws + 75497472);
  float* COS    = (float*)(ws + 75759616);

  k_cvt_bf16<<<2048, 256, 0, stream>>>(x, XB);
  k_transpose_cvt<<<32 * 96, 256, 0, stream>>>(Wqkv, WQKVT, 3072);
  k_transpose_cvt<<<32 * 32, 256, 0, stream>>>(Wproj, WPROJT, 1024);
  k_tables<<<256, 256, 0, stream>>>(pos, SIN, COS);
  k_gemm<3072, false><<<32 * 24, 256, 0, stream>>>(XB, WQKVT, bqkv, QKV);
  k_rope<<<32 * 32, 256, 0, stream>>>(QKV, SIN, COS, QR, KR, VT);
  k_attn<<<1024, 256, 0, stream>>>(QR, KR, VT, AO);
  k_gemm<1024, true><<<32 * 8, 256, 0, stream>>>(AO, WPROJT, bproj, d_out);
}

// Round 2
// 250.067 us; speedup vs baseline: 2.0757x; 2.0757x over previous
//
#include <hip/hip_runtime.h>
#include <hip/hip_bf16.h>
#include <stdint.h>

#define DEV __device__ __forceinline__

typedef unsigned short u16;
typedef unsigned int   u32;
typedef __attribute__((ext_vector_type(8))) short bf16x8;   // 8 bf16 = 4 VGPRs
typedef __attribute__((ext_vector_type(4))) float f32x4;
typedef __attribute__((ext_vector_type(4))) u32   u32x4;
typedef __attribute__((ext_vector_type(2))) u32   u32x2;

// ---- numeric helpers -------------------------------------------------------
DEV u16 f2bf(float f) {            // RNE f32 -> bf16
  u32 u = __builtin_bit_cast(u32, f);
  u = (u + 0x7fffu + ((u >> 16) & 1u)) >> 16;
  return (u16)u;
}
DEV float bf2f(u16 h) { return __builtin_bit_cast(float, (u32)h << 16); }
DEV u32 pk2(float a, float b) {    // pack 2 f32 -> 2 bf16 in one u32 (RNE)
  u32 x = __builtin_bit_cast(u32, a), y = __builtin_bit_cast(u32, b);
  x = (x + 0x7fffu + ((x >> 16) & 1u)) >> 16;
  y = (y + 0x7fffu + ((y >> 16) & 1u)) >> 16;
  return x | (y << 16);
}
DEV f32x4 mfma16(bf16x8 a, bf16x8 b, f32x4 c) {
  return __builtin_amdgcn_mfma_f32_16x16x32_bf16(a, b, c, 0, 0, 0);
}
DEV void gload16(const void* g, void* l) {   // global -> LDS direct, 16B/lane
  __builtin_amdgcn_global_load_lds(
      (const __attribute__((address_space(1))) void*)g,
      (__attribute__((address_space(3))) void*)l, 16, 0, 0);
}

// ---- problem constants -----------------------------------------------------
// B=2 T=2048 DIM=1024 HEADS=16 HEAD_DIM=64; tokens = 4096
// workspace layout (bytes):
//  XB      0         x as bf16            [4096][1024]
//  WQKVT   8388608   Wqkv^T bf16          [3072][1024]
//  WPROJT  14680064  Wproj^T bf16         [1024][1024]
//  QKV     16777216  qkv bf16             [4096][3072]
//  QR      41943040  roped*scale Q bf16   [32][2048][64]
//  KR      50331648  roped K bf16         [32][2048][64]
//  VT      58720256  V^T bf16             [32][64][2048]
//  AO      67108864  attn out bf16        [4096][1024]
//  SIN     75497472  f32 [2048][32]
//  COS     75759616  f32 [2048][32]

// ---- prep kernels ----------------------------------------------------------
__global__ __launch_bounds__(256) void k_cvt_bf16(const float* __restrict__ in,
                                                  u16* __restrict__ out) {
  size_t i = ((size_t)blockIdx.x * 256 + threadIdx.x) * 8;
  float4 a = *(const float4*)(in + i);
  float4 b = *(const float4*)(in + i + 4);
  u32x4 o = { pk2(a.x, a.y), pk2(a.z, a.w), pk2(b.x, b.y), pk2(b.z, b.w) };
  *(u32x4*)(out + i) = o;
}

// W [1024][Ndim] f32 -> WT [Ndim][1024] bf16 (coalesced both sides via LDS)
__global__ __launch_bounds__(256) void k_transpose_cvt(const float* __restrict__ W,
                                                       u16* __restrict__ WT,
                                                       int Ndim) {
  int bk = blockIdx.x & 31;        // K/32 = 32
  int bn = blockIdx.x >> 5;
  int k0 = bk * 32, n0 = bn * 32;
  __shared__ float t[32][33];
  int tx = threadIdx.x & 31, ty = threadIdx.x >> 5; // ty 0..7
#pragma unroll
  for (int i = 0; i < 4; ++i)
    t[ty + 8 * i][tx] = W[(size_t)(k0 + ty + 8 * i) * Ndim + n0 + tx];
  __syncthreads();
#pragma unroll
  for (int i = 0; i < 4; ++i) {
    int n = ty + 8 * i;
    WT[(size_t)(n0 + n) * 1024 + k0 + tx] = f2bf(t[tx][n]);
  }
}

__global__ __launch_bounds__(256) void k_tables(const int* __restrict__ posp,
                                                float* __restrict__ sint,
                                                float* __restrict__ cost) {
  int i = blockIdx.x * 256 + threadIdx.x;   // 65536 = 2048*32
  int t = i >> 5, d = i & 31;
  float theta = exp2f(-(float)d * (13.2877123795494f / 32.0f));
  float ang = (float)(posp[0] + t) * theta;
  sint[i] = sinf(ang);
  cost[i] = cosf(ang);
}

// ---- GEMM: C[4096][N] = A[4096][1024] @ BT^T + bias ------------------------
// 128x128 tile, BK=32, 4 waves (2x2 of 64x64), mfma 16x16x32 bf16.
// Staging: global_load_lds width=16, linear LDS dest, swizzle applied on the
// GLOBAL source address (rule #21: both-sides-or-neither). Reads use the same
// XOR chunk swizzle c ^ ((r>>1)&3) -> 2-way max bank aliasing on ds_read_b128.
template <int N, bool OUTF32>
__global__ __launch_bounds__(256, 2) void k_gemm(const u16* __restrict__ A,
                                                 const u16* __restrict__ BT,
                                                 const float* __restrict__ bias,
                                                 void* __restrict__ Cout) {
  constexpr int K = 1024;
  int bm = blockIdx.x & 31;             // M/128 = 32
  int bn = blockIdx.x >> 5;
  int m0 = bm * 128, n0 = bn * 128;
  int tid = threadIdx.x, lane = tid & 63, w = tid >> 6;
  int g = lane >> 4, l15 = lane & 15;
  int wr = w >> 1, wc = w & 1;

  __shared__ u16 Alds[128 * 32];
  __shared__ u16 Blds[128 * 32];

  f32x4 acc[4][4] = {};

  // staging geometry: wave w covers rows {w*16 + (lane>>2)} and +64.
  // linear LDS slot c = lane&3 receives global chunk (lane&3) ^ ((lane>>3)&3)
  int rowW = w * 16 + (lane >> 2);
  int cSrc = (lane & 3) ^ ((lane >> 3) & 3);
  const u16* Ag0 = A  + (size_t)(m0 + rowW) * K + cSrc * 8;
  const u16* Ag1 = A  + (size_t)(m0 + 64 + rowW) * K + cSrc * 8;
  const u16* Bg0 = BT + (size_t)(n0 + rowW) * K + cSrc * 8;
  const u16* Bg1 = BT + (size_t)(n0 + 64 + rowW) * K + cSrc * 8;
  char* AldsW0 = (char*)Alds + w * 1024;          // + lane*16 by HW
  char* AldsW1 = (char*)Alds + 4096 + w * 1024;
  char* BldsW0 = (char*)Blds + w * 1024;
  char* BldsW1 = (char*)Blds + 4096 + w * 1024;

  for (int k0 = 0; k0 < K; k0 += 32) {
    gload16(Ag0 + k0, AldsW0);
    gload16(Ag1 + k0, AldsW1);
    gload16(Bg0 + k0, BldsW0);
    gload16(Bg1 + k0, BldsW1);
    __syncthreads();                    // drains vmcnt (compiler-inserted)
    bf16x8 af[4], bf_[4];
#pragma unroll
    for (int m = 0; m < 4; ++m) {
      int r = wr * 64 + m * 16 + l15;
      af[m] = *(const bf16x8*)((const char*)Alds + r * 64 + ((g ^ ((r >> 1) & 3)) << 4));
    }
#pragma unroll
    for (int n = 0; n < 4; ++n) {
      int r = wc * 64 + n * 16 + l15;
      bf_[n] = *(const bf16x8*)((const char*)Blds + r * 64 + ((g ^ ((r >> 1) & 3)) << 4));
    }
#pragma unroll
    for (int m = 0; m < 4; ++m)
#pragma unroll
      for (int n = 0; n < 4; ++n)
        acc[m][n] = mfma16(af[m], bf_[n], acc[m][n]);
    __syncthreads();
  }

  // epilogue: D row = 4*g + j (per 16-block), col = l15
#pragma unroll
  for (int m = 0; m < 4; ++m) {
    int rowb = m0 + wr * 64 + m * 16 + 4 * g;
#pragma unroll
    for (int n = 0; n < 4; ++n) {
      int col = n0 + wc * 64 + n * 16 + l15;
      float bv = bias[col];
#pragma unroll
      for (int j = 0; j < 4; ++j) {
        float v = acc[m][n][j] + bv;
        if constexpr (OUTF32)
          ((float*)Cout)[(size_t)(rowb + j) * N + col] = v;
        else
          ((u16*)Cout)[(size_t)(rowb + j) * N + col] = f2bf(v);
      }
    }
  }
}

// ---- RoPE + head reshape + V transpose -------------------------------------
__global__ __launch_bounds__(256) void k_rope(const u16* __restrict__ qkv,
                                              const float* __restrict__ sint,
                                              const float* __restrict__ cost,
                                              u16* __restrict__ QR,
                                              u16* __restrict__ KR,
                                              u16* __restrict__ VT) {
  int bid = blockIdx.x;
  int bh = bid >> 5;                 // T/64 = 32 blocks per (b,h)
  int t0 = (bid & 31) * 64;
  int b = bh >> 4, h = bh & 15;
  int tid = threadIdx.x;

  int dp = tid & 31;
  int tt0 = tid >> 5;                 // 0..7
#pragma unroll
  for (int r = 0; r < 8; ++r) {
    int tl = r * 8 + tt0;
    int t = t0 + tl;
    int tok = b * 2048 + t;
    const u16* row = qkv + (size_t)tok * 3072;
    float sn = sint[t * 32 + dp], cs = cost[t * 32 + dp];

    u32 qq = *(const u32*)(row + h * 64 + 2 * dp);
    float x1 = bf2f((u16)qq), x2 = bf2f((u16)(qq >> 16));
    u16* qo = QR + ((size_t)bh * 2048 + t) * 64;
    qo[dp]      = f2bf(0.125f * (x1 * cs - x2 * sn));
    qo[dp + 32] = f2bf(0.125f * (x1 * sn + x2 * cs));

    u32 kk = *(const u32*)(row + 1024 + h * 64 + 2 * dp);
    x1 = bf2f((u16)kk); x2 = bf2f((u16)(kk >> 16));
    u16* ko = KR + ((size_t)bh * 2048 + t) * 64;
    ko[dp]      = f2bf(x1 * cs - x2 * sn);
    ko[dp + 32] = f2bf(x1 * sn + x2 * cs);
  }

  __shared__ u16 vld[64][72];
#pragma unroll
  for (int it = 0; it < 2; ++it) {
    int slot = it * 256 + tid;
    int tl = slot >> 3, ch = slot & 7;
    int tok = b * 2048 + t0 + tl;
    uint4 v = *(const uint4*)(qkv + (size_t)tok * 3072 + 2048 + h * 64 + ch * 8);
    *(uint4*)&vld[tl][ch * 8] = v;
  }
  __syncthreads();
#pragma unroll
  for (int it = 0; it < 2; ++it) {
    int slot = it * 256 + tid;
    int d = slot >> 3, tch = slot & 7;
    u16 tmp[8];
#pragma unroll
    for (int i = 0; i < 8; ++i) tmp[i] = vld[tch * 8 + i][d];
    u32x4 o = { (u32)tmp[0] | ((u32)tmp[1] << 16), (u32)tmp[2] | ((u32)tmp[3] << 16),
                (u32)tmp[4] | ((u32)tmp[5] << 16), (u32)tmp[6] | ((u32)tmp[7] << 16) };
    *(u32x4*)(VT + ((size_t)bh * 64 + d) * 2048 + t0 + tch * 8) = o;
  }
}

// ---- causal flash attention, pair-balanced ---------------------------------
// Each wave owns q-tiles {qtA = 127-pr, qtB = pr}: uniform ~34 key-tiles per
// wave (perfect causal balance). Light tile B reuses the SAME K registers as A.
// K double-buffered (prefetch under softmax+PV); V issued at step start.
// Block->bh mapping is XCD-aware: each XCD works 4 bh at a time (2MB K/V in L2).
__global__ __launch_bounds__(256, 2) void k_attn(const u16* __restrict__ QR,
                                                 const u16* __restrict__ KR,
                                                 const u16* __restrict__ VT,
                                                 u16* __restrict__ AO) {
  int tid = threadIdx.x;
  int w = tid >> 6, lane = tid & 63;
  int g = lane >> 4, l15 = lane & 15;

  int x = blockIdx.x & 7;            // XCD slot
  int i = blockIdx.x >> 3;           // 0..63
  int bh = x + 8 * (i >> 4);         // 4 bh per XCD slot
  int pr = (i & 15) * 4 + w;         // 0..63
  int qtA = 127 - pr, qtB = pr;
  int q0A = qtA * 16, q0B = qtB * 16;
  int b = bh >> 4, h = bh & 15;
  int qaA = q0A + l15, qaB = q0B + l15;

  const u16* QrA = QR + ((size_t)bh * 2048 + q0A + l15) * 64 + 8 * g;
  bf16x8 qA0 = *(const bf16x8*)(QrA);
  bf16x8 qA1 = *(const bf16x8*)(QrA + 32);
  const u16* QrB = QR + ((size_t)bh * 2048 + q0B + l15) * 64 + 8 * g;
  bf16x8 qB0 = *(const bf16x8*)(QrB);
  bf16x8 qB1 = *(const bf16x8*)(QrB + 32);

  const u16* Kbase = KR + (size_t)bh * 2048 * 64;
  const u16* Vbase = VT + (size_t)bh * 64 * 2048;

  f32x4 oA[4] = {}, oB[4] = {};
  float mA = -1e30f, lA = 0.f, mB = -1e30f, lB = 0.f;
  int nA = qtA / 4 + 1, nB = qtB / 4 + 1;   // nA >= 17 > 16 >= nB

  auto loadK = [&](int tk0, bf16x8 (&kf)[8]) {
#pragma unroll
    for (int blk = 0; blk < 4; ++blk) {
      const u16* krow = Kbase + (size_t)((tk0 + blk * 16 + l15) * 64) + 8 * g;
      kf[2 * blk]     = *(const bf16x8*)krow;
      kf[2 * blk + 1] = *(const bf16x8*)(krow + 32);
    }
  };

  // softmax + PV for one q-sub-tile (lane owns column q; rows tk in 16 regs)
  auto smpv = [&](f32x4 (&sb)[4], float& m_run, float& l_run, f32x4 (&oacc)[4],
                  const u32x4 (&vf)[8]) {
    float mx = sb[0][0];
#pragma unroll
    for (int blk = 0; blk < 4; ++blk)
#pragma unroll
      for (int j = 0; j < 4; ++j) mx = fmaxf(mx, sb[blk][j]);
    mx = fmaxf(mx, __shfl_xor(mx, 16));
    mx = fmaxf(mx, __shfl_xor(mx, 32));
    float mnew = fmaxf(m_run, mx);
    float alpha = exp2f((m_run - mnew) * 1.44269504f);
    float p[4][4];
    float psum = 0.f;
#pragma unroll
    for (int blk = 0; blk < 4; ++blk)
#pragma unroll
      for (int j = 0; j < 4; ++j) {
        float pv = exp2f((sb[blk][j] - mnew) * 1.44269504f);
        p[blk][j] = pv;
        psum += pv;
      }
    psum += __shfl_xor(psum, 16);
    psum += __shfl_xor(psum, 32);
    l_run = l_run * alpha + psum;
    m_run = mnew;
#pragma unroll
    for (int dblk = 0; dblk < 4; ++dblk) oacc[dblk] *= alpha;
#pragma unroll
    for (int s2 = 0; s2 < 2; ++s2) {
      u32x4 pu = { pk2(p[2 * s2][0], p[2 * s2][1]),
                   pk2(p[2 * s2][2], p[2 * s2][3]),
                   pk2(p[2 * s2 + 1][0], p[2 * s2 + 1][1]),
                   pk2(p[2 * s2 + 1][2], p[2 * s2 + 1][3]) };
      bf16x8 pb = __builtin_bit_cast(bf16x8, pu);
#pragma unroll
      for (int dblk = 0; dblk < 4; ++dblk) {
        bf16x8 va = __builtin_bit_cast(bf16x8, vf[s2 * 4 + dblk]);
        oacc[dblk] = mfma16(va, pb, oacc[dblk]);
      }
    }
  };

  auto step = [&](int t, bf16x8 (&kc)[8], bf16x8 (&kn)[8]) {
    int tk0 = t * 64;
    bool actB = (t < nB);
    // V for THIS tile: issue early, consumed after S+softmax (~300-400 cyc)
    u32x4 vf[8];
#pragma unroll
    for (int s2 = 0; s2 < 2; ++s2)
#pragma unroll
      for (int dblk = 0; dblk < 4; ++dblk) {
        const u16* vrow = Vbase + (size_t)((dblk * 16 + l15) * 2048) + tk0 + 32 * s2 + 4 * g;
        uint2 lo = *(const uint2*)vrow;
        uint2 hi = *(const uint2*)(vrow + 16);
        vf[s2 * 4 + dblk] = u32x4{ lo.x, lo.y, hi.x, hi.y };
      }
    // S^T = K·Q for both q-tiles, sharing K registers
    f32x4 sA[4], sB[4];
#pragma unroll
    for (int blk = 0; blk < 4; ++blk) {
      f32x4 z = { 0.f, 0.f, 0.f, 0.f };
      z = mfma16(kc[2 * blk], qA0, z);
      sA[blk] = mfma16(kc[2 * blk + 1], qA1, z);
    }
    if (actB) {
#pragma unroll
      for (int blk = 0; blk < 4; ++blk) {
        f32x4 z = { 0.f, 0.f, 0.f, 0.f };
        z = mfma16(kc[2 * blk], qB0, z);
        sB[blk] = mfma16(kc[2 * blk + 1], qB1, z);
      }
    }
    // prefetch next K under softmax+PV
    if (t + 1 < nA) loadK((t + 1) * 64, kn);
    // causal masks (only final tile of each range)
    if (t == nA - 1) {
#pragma unroll
      for (int blk = 0; blk < 4; ++blk)
#pragma unroll
        for (int j = 0; j < 4; ++j) {
          int tk = tk0 + blk * 16 + 4 * g + j;
          if (tk > qaA) sA[blk][j] = -1e30f;
        }
    }
    smpv(sA, mA, lA, oA, vf);
    if (actB) {
      if (t == nB - 1) {
#pragma unroll
        for (int blk = 0; blk < 4; ++blk)
#pragma unroll
          for (int j = 0; j < 4; ++j) {
            int tk = tk0 + blk * 16 + 4 * g + j;
            if (tk > qaB) sB[blk][j] = -1e30f;
          }
      }
      smpv(sB, mB, lB, oB, vf);
    }
  };

  bf16x8 kbuf0[8], kbuf1[8];
  loadK(0, kbuf0);
  for (int t = 0; t < nA; t += 2) {
    step(t, kbuf0, kbuf1);
    if (t + 1 < nA) step(t + 1, kbuf1, kbuf0);
  }

  float invA = 1.0f / lA;
  u16* orA = AO + ((size_t)b * 2048 + q0A + l15) * 1024 + h * 64 + 4 * g;
#pragma unroll
  for (int dblk = 0; dblk < 4; ++dblk) {
    u32x2 o = { pk2(oA[dblk][0] * invA, oA[dblk][1] * invA),
                pk2(oA[dblk][2] * invA, oA[dblk][3] * invA) };
    *(u32x2*)(orA + dblk * 16) = o;
  }
  float invB = 1.0f / lB;
  u16* orB = AO + ((size_t)b * 2048 + q0B + l15) * 1024 + h * 64 + 4 * g;
#pragma unroll
  for (int dblk = 0; dblk < 4; ++dblk) {
    u32x2 o = { pk2(oB[dblk][0] * invB, oB[dblk][1] * invB),
                pk2(oB[dblk][2] * invB, oB[dblk][3] * invB) };
    *(u32x2*)(orB + dblk * 16) = o;
  }
}

// ---- launcher ---------------------------------------------------------------
extern "C" void kernel_launch(void* const* d_in, const int* in_sizes, int n_in,
                              void* d_out, int out_size, void* d_ws, size_t ws_size,
                              hipStream_t stream) {
  (void)in_sizes; (void)n_in; (void)out_size; (void)ws_size;
  const float* x     = (const float*)d_in[0];
  const float* Wqkv  = (const float*)d_in[1];
  const float* bqkv  = (const float*)d_in[2];
  const float* Wproj = (const float*)d_in[3];
  const float* bproj = (const float*)d_in[4];
  const int*   pos   = (const int*)d_in[5];

  char* ws = (char*)d_ws;
  u16*   XB     = (u16*)(ws + 0);
  u16*   WQKVT  = (u16*)(ws + 8388608);
  u16*   WPROJT = (u16*)(ws + 14680064);
  u16*   QKV    = (u16*)(ws + 16777216);
  u16*   QR     = (u16*)(ws + 41943040);
  u16*   KR     = (u16*)(ws + 50331648);
  u16*   VT     = (u16*)(ws + 58720256);
  u16*   AO     = (u16*)(ws + 67108864);
  float* SIN    = (float*)(ws + 75497472);
  float* COS    = (float*)(ws + 75759616);

  k_cvt_bf16<<<2048, 256, 0, stream>>>(x, XB);
  k_transpose_cvt<<<32 * 96, 256, 0, stream>>>(Wqkv, WQKVT, 3072);
  k_transpose_cvt<<<32 * 32, 256, 0, stream>>>(Wproj, WPROJT, 1024);
  k_tables<<<256, 256, 0, stream>>>(pos, SIN, COS);
  k_gemm<3072, false><<<32 * 24, 256, 0, stream>>>(XB, WQKVT, bqkv, QKV);
  k_rope<<<32 * 32, 256, 0, stream>>>(QKV, SIN, COS, QR, KR, VT);
  k_attn<<<512, 256, 0, stream>>>(QR, KR, VT, AO);
  k_gemm<1024, true><<<32 * 8, 256, 0, stream>>>(AO, WPROJT, bproj, d_out);
}

// Round 3
// 141.728 us; speedup vs baseline: 3.6624x; 1.7644x over previous
//
#include <hip/hip_runtime.h>
#include <hip/hip_bf16.h>
#include <stdint.h>

#define DEV __device__ __forceinline__

typedef unsigned short u16;
typedef unsigned int   u32;
typedef __attribute__((ext_vector_type(8))) short bf16x8;   // 8 bf16 = 4 VGPRs
typedef __attribute__((ext_vector_type(4))) float f32x4;
typedef __attribute__((ext_vector_type(4))) u32   u32x4;
typedef __attribute__((ext_vector_type(2))) u32   u32x2;

// ---- numeric helpers -------------------------------------------------------
DEV u16 f2bf(float f) {            // RNE f32 -> bf16
  u32 u = __builtin_bit_cast(u32, f);
  u = (u + 0x7fffu + ((u >> 16) & 1u)) >> 16;
  return (u16)u;
}
DEV float bf2f(u16 h) { return __builtin_bit_cast(float, (u32)h << 16); }
DEV u32 pk2(float a, float b) {    // pack 2 f32 -> 2 bf16 in one u32 (RNE)
  u32 x = __builtin_bit_cast(u32, a), y = __builtin_bit_cast(u32, b);
  x = (x + 0x7fffu + ((x >> 16) & 1u)) >> 16;
  y = (y + 0x7fffu + ((y >> 16) & 1u)) >> 16;
  return x | (y << 16);
}
DEV f32x4 mfma16(bf16x8 a, bf16x8 b, f32x4 c) {
  return __builtin_amdgcn_mfma_f32_16x16x32_bf16(a, b, c, 0, 0, 0);
}
DEV void gload16(const void* g, void* l) {   // global -> LDS direct, 16B/lane
  __builtin_amdgcn_global_load_lds(
      (const __attribute__((address_space(1))) void*)g,
      (__attribute__((address_space(3))) void*)l, 16, 0, 0);
}

// ---- problem constants -----------------------------------------------------
// B=2 T=2048 DIM=1024 HEADS=16 HEAD_DIM=64; tokens = 4096
// workspace layout (bytes):
//  XB      0         x as bf16            [4096][1024]
//  WQKVT   8388608   Wqkv^T bf16          [3072][1024]
//  WPROJT  14680064  Wproj^T bf16         [1024][1024]
//  QKV     16777216  qkv bf16             [4096][3072]
//  QR      41943040  roped*scale Q bf16   [32][2048][64]
//  KR      50331648  roped K bf16         [32][2048][64]
//  VT      58720256  V^T bf16             [32][64][2048]
//  AO      67108864  attn out bf16        [4096][1024]
//  SIN     75497472  f32 [2048][32]
//  COS     75759616  f32 [2048][32]

// ---- prep kernels ----------------------------------------------------------
__global__ __launch_bounds__(256) void k_cvt_bf16(const float* __restrict__ in,
                                                  u16* __restrict__ out) {
  size_t i = ((size_t)blockIdx.x * 256 + threadIdx.x) * 8;
  float4 a = *(const float4*)(in + i);
  float4 b = *(const float4*)(in + i + 4);
  u32x4 o = { pk2(a.x, a.y), pk2(a.z, a.w), pk2(b.x, b.y), pk2(b.z, b.w) };
  *(u32x4*)(out + i) = o;
}

// W [1024][Ndim] f32 -> WT [Ndim][1024] bf16 (coalesced both sides via LDS)
__global__ __launch_bounds__(256) void k_transpose_cvt(const float* __restrict__ W,
                                                       u16* __restrict__ WT,
                                                       int Ndim) {
  int bk = blockIdx.x & 31;        // K/32 = 32
  int bn = blockIdx.x >> 5;
  int k0 = bk * 32, n0 = bn * 32;
  __shared__ float t[32][33];
  int tx = threadIdx.x & 31, ty = threadIdx.x >> 5; // ty 0..7
#pragma unroll
  for (int i = 0; i < 4; ++i)
    t[ty + 8 * i][tx] = W[(size_t)(k0 + ty + 8 * i) * Ndim + n0 + tx];
  __syncthreads();
#pragma unroll
  for (int i = 0; i < 4; ++i) {
    int n = ty + 8 * i;
    WT[(size_t)(n0 + n) * 1024 + k0 + tx] = f2bf(t[tx][n]);
  }
}

__global__ __launch_bounds__(256) void k_tables(const int* __restrict__ posp,
                                                float* __restrict__ sint,
                                                float* __restrict__ cost) {
  int i = blockIdx.x * 256 + threadIdx.x;   // 65536 = 2048*32
  int t = i >> 5, d = i & 31;
  float theta = exp2f(-(float)d * (13.2877123795494f / 32.0f));
  float ang = (float)(posp[0] + t) * theta;
  sint[i] = sinf(ang);
  cost[i] = cosf(ang);
}

// ---- GEMM: C[4096][N] = A[4096][1024] @ BT^T + bias ------------------------
// 128x128 tile, BK=32, 4 waves (2x2 of 64x64), mfma 16x16x32 bf16.
// Staging: global_load_lds width=16, linear LDS dest, swizzle applied on the
// GLOBAL source address (rule #21). Reads use the same XOR chunk swizzle.
template <int N, bool OUTF32>
__global__ __launch_bounds__(256, 2) void k_gemm(const u16* __restrict__ A,
                                                 const u16* __restrict__ BT,
                                                 const float* __restrict__ bias,
                                                 void* __restrict__ Cout) {
  constexpr int K = 1024;
  int bm = blockIdx.x & 31;             // M/128 = 32
  int bn = blockIdx.x >> 5;
  int m0 = bm * 128, n0 = bn * 128;
  int tid = threadIdx.x, lane = tid & 63, w = tid >> 6;
  int g = lane >> 4, l15 = lane & 15;
  int wr = w >> 1, wc = w & 1;

  __shared__ u16 Alds[128 * 32];
  __shared__ u16 Blds[128 * 32];

  f32x4 acc[4][4] = {};

  int rowW = w * 16 + (lane >> 2);
  int cSrc = (lane & 3) ^ ((lane >> 3) & 3);
  const u16* Ag0 = A  + (size_t)(m0 + rowW) * K + cSrc * 8;
  const u16* Ag1 = A  + (size_t)(m0 + 64 + rowW) * K + cSrc * 8;
  const u16* Bg0 = BT + (size_t)(n0 + rowW) * K + cSrc * 8;
  const u16* Bg1 = BT + (size_t)(n0 + 64 + rowW) * K + cSrc * 8;
  char* AldsW0 = (char*)Alds + w * 1024;          // + lane*16 by HW
  char* AldsW1 = (char*)Alds + 4096 + w * 1024;
  char* BldsW0 = (char*)Blds + w * 1024;
  char* BldsW1 = (char*)Blds + 4096 + w * 1024;

  for (int k0 = 0; k0 < K; k0 += 32) {
    gload16(Ag0 + k0, AldsW0);
    gload16(Ag1 + k0, AldsW1);
    gload16(Bg0 + k0, BldsW0);
    gload16(Bg1 + k0, BldsW1);
    __syncthreads();                    // drains vmcnt (compiler-inserted)
    bf16x8 af[4], bf_[4];
#pragma unroll
    for (int m = 0; m < 4; ++m) {
      int r = wr * 64 + m * 16 + l15;
      af[m] = *(const bf16x8*)((const char*)Alds + r * 64 + ((g ^ ((r >> 1) & 3)) << 4));
    }
#pragma unroll
    for (int n = 0; n < 4; ++n) {
      int r = wc * 64 + n * 16 + l15;
      bf_[n] = *(const bf16x8*)((const char*)Blds + r * 64 + ((g ^ ((r >> 1) & 3)) << 4));
    }
#pragma unroll
    for (int m = 0; m < 4; ++m)
#pragma unroll
      for (int n = 0; n < 4; ++n)
        acc[m][n] = mfma16(af[m], bf_[n], acc[m][n]);
    __syncthreads();
  }

#pragma unroll
  for (int m = 0; m < 4; ++m) {
    int rowb = m0 + wr * 64 + m * 16 + 4 * g;
#pragma unroll
    for (int n = 0; n < 4; ++n) {
      int col = n0 + wc * 64 + n * 16 + l15;
      float bv = bias[col];
#pragma unroll
      for (int j = 0; j < 4; ++j) {
        float v = acc[m][n][j] + bv;
        if constexpr (OUTF32)
          ((float*)Cout)[(size_t)(rowb + j) * N + col] = v;
        else
          ((u16*)Cout)[(size_t)(rowb + j) * N + col] = f2bf(v);
      }
    }
  }
}

// ---- RoPE + head reshape + V transpose -------------------------------------
__global__ __launch_bounds__(256) void k_rope(const u16* __restrict__ qkv,
                                              const float* __restrict__ sint,
                                              const float* __restrict__ cost,
                                              u16* __restrict__ QR,
                                              u16* __restrict__ KR,
                                              u16* __restrict__ VT) {
  int bid = blockIdx.x;
  int bh = bid >> 5;                 // T/64 = 32 blocks per (b,h)
  int t0 = (bid & 31) * 64;
  int b = bh >> 4, h = bh & 15;
  int tid = threadIdx.x;

  int dp = tid & 31;
  int tt0 = tid >> 5;                 // 0..7
#pragma unroll
  for (int r = 0; r < 8; ++r) {
    int tl = r * 8 + tt0;
    int t = t0 + tl;
    int tok = b * 2048 + t;
    const u16* row = qkv + (size_t)tok * 3072;
    float sn = sint[t * 32 + dp], cs = cost[t * 32 + dp];

    u32 qq = *(const u32*)(row + h * 64 + 2 * dp);
    float x1 = bf2f((u16)qq), x2 = bf2f((u16)(qq >> 16));
    u16* qo = QR + ((size_t)bh * 2048 + t) * 64;
    qo[dp]      = f2bf(0.125f * (x1 * cs - x2 * sn));
    qo[dp + 32] = f2bf(0.125f * (x1 * sn + x2 * cs));

    u32 kk = *(const u32*)(row + 1024 + h * 64 + 2 * dp);
    x1 = bf2f((u16)kk); x2 = bf2f((u16)(kk >> 16));
    u16* ko = KR + ((size_t)bh * 2048 + t) * 64;
    ko[dp]      = f2bf(x1 * cs - x2 * sn);
    ko[dp + 32] = f2bf(x1 * sn + x2 * cs);
  }

  __shared__ u16 vld[64][72];
#pragma unroll
  for (int it = 0; it < 2; ++it) {
    int slot = it * 256 + tid;
    int tl = slot >> 3, ch = slot & 7;
    int tok = b * 2048 + t0 + tl;
    uint4 v = *(const uint4*)(qkv + (size_t)tok * 3072 + 2048 + h * 64 + ch * 8);
    *(uint4*)&vld[tl][ch * 8] = v;
  }
  __syncthreads();
#pragma unroll
  for (int it = 0; it < 2; ++it) {
    int slot = it * 256 + tid;
    int d = slot >> 3, tch = slot & 7;
    u16 tmp[8];
#pragma unroll
    for (int i = 0; i < 8; ++i) tmp[i] = vld[tch * 8 + i][d];
    u32x4 o = { (u32)tmp[0] | ((u32)tmp[1] << 16), (u32)tmp[2] | ((u32)tmp[3] << 16),
                (u32)tmp[4] | ((u32)tmp[5] << 16), (u32)tmp[6] | ((u32)tmp[7] << 16) };
    *(u32x4*)(VT + ((size_t)bh * 64 + d) * 2048 + t0 + tch * 8) = o;
  }
}

// ---- causal flash attention: block-cooperative LDS K/V, pair-balanced ------
// 64-row q-tiles; block owns pair (tA=31-i, tB=i) -> uniform nA+nB=33 steps.
// Wave w handles 16-row subtiles of A and B. K/V staged per key-tile into
// double-buffered LDS via global_load_lds (async), XOR swizzle chunk^=(row&7)
// pre-applied on global source, same XOR on ds_reads (<=2-way conflicts).
__global__ __launch_bounds__(256, 2) void k_attn(const u16* __restrict__ QR,
                                                 const u16* __restrict__ KR,
                                                 const u16* __restrict__ VT,
                                                 u16* __restrict__ AO) {
  int tid = threadIdx.x;
  int w = tid >> 6, lane = tid & 63;
  int g = lane >> 4, l15 = lane & 15;

  int x = blockIdx.x & 7;            // XCD slot
  int i = blockIdx.x >> 3;           // 0..63
  int bh = x + 8 * (i >> 4);         // 4 bh per XCD slot -> 2MB KV in L2
  int pi = i & 15;                   // pair 0..15
  int tA = 31 - pi, tB = pi;         // 64-row q-tile indices
  int nA = tA + 1, nB = tB + 1;      // key tiles (64 keys each); nB <= nA
  int b = bh >> 4, h = bh & 15;
  int q0A = tA * 64 + w * 16;        // wave's 16-row subtiles
  int q0B = tB * 64 + w * 16;
  int qaA = q0A + l15, qaB = q0B + l15;

  const u16* Kg = KR + (size_t)bh * 2048 * 64;
  const u16* Vg = VT + (size_t)bh * 64 * 2048;

  __shared__ u16 Klds[2][64 * 64];   // 8KB per buf, row = 64 bf16 = 8 chunks
  __shared__ u16 Vlds[2][64 * 64];   // d-major, row = 64 keys

  const u16* QrA = QR + ((size_t)bh * 2048 + q0A + l15) * 64 + 8 * g;
  bf16x8 qA0 = *(const bf16x8*)(QrA);
  bf16x8 qA1 = *(const bf16x8*)(QrA + 32);
  const u16* QrB = QR + ((size_t)bh * 2048 + q0B + l15) * 64 + 8 * g;
  bf16x8 qB0 = *(const bf16x8*)(QrB);
  bf16x8 qB1 = *(const bf16x8*)(QrB + 32);

  f32x4 oA[4] = {}, oB[4] = {};
  float mA = -1e30f, lAs = 0.f, mB = -1e30f, lBs = 0.f;

  int rstg = lane >> 3;              // 0..7 (row within 8-row issue)
  int cswz = (lane & 7) ^ rstg;      // pre-swizzled source chunk

  // wave w stages rows [w*16, w*16+16) of both K and V tiles (4 issues)
  auto stage = [&](int kt, int bufb) {
#pragma unroll
    for (int j = 0; j < 2; ++j) {
      int r = w * 16 + j * 8 + rstg;
      gload16(Kg + (size_t)(kt * 64 + r) * 64 + cswz * 8,
              &Klds[bufb][(w * 16 + j * 8) * 64]);
      gload16(Vg + (size_t)r * 2048 + kt * 64 + cswz * 8,
              &Vlds[bufb][(w * 16 + j * 8) * 64]);
    }
  };

  auto smpv = [&](f32x4 (&sb)[4], float& m_run, float& l_run, f32x4 (&oacc)[4],
                  const u32x4 (&vf)[8]) {
    float mx = sb[0][0];
#pragma unroll
    for (int blk = 0; blk < 4; ++blk)
#pragma unroll
      for (int j = 0; j < 4; ++j) mx = fmaxf(mx, sb[blk][j]);
    mx = fmaxf(mx, __shfl_xor(mx, 16));
    mx = fmaxf(mx, __shfl_xor(mx, 32));
    float mnew = fmaxf(m_run, mx);
    float alpha = exp2f((m_run - mnew) * 1.44269504f);
    float p[4][4];
    float psum = 0.f;
#pragma unroll
    for (int blk = 0; blk < 4; ++blk)
#pragma unroll
      for (int j = 0; j < 4; ++j) {
        float pv = exp2f((sb[blk][j] - mnew) * 1.44269504f);
        p[blk][j] = pv;
        psum += pv;
      }
    psum += __shfl_xor(psum, 16);
    psum += __shfl_xor(psum, 32);
    l_run = l_run * alpha + psum;
    m_run = mnew;
#pragma unroll
    for (int dblk = 0; dblk < 4; ++dblk) oacc[dblk] *= alpha;
#pragma unroll
    for (int s2 = 0; s2 < 2; ++s2) {
      u32x4 pu = { pk2(p[2 * s2][0], p[2 * s2][1]),
                   pk2(p[2 * s2][2], p[2 * s2][3]),
                   pk2(p[2 * s2 + 1][0], p[2 * s2 + 1][1]),
                   pk2(p[2 * s2 + 1][2], p[2 * s2 + 1][3]) };
      bf16x8 pb = __builtin_bit_cast(bf16x8, pu);
#pragma unroll
      for (int dblk = 0; dblk < 4; ++dblk) {
        bf16x8 va = __builtin_bit_cast(bf16x8, vf[s2 * 4 + dblk]);
        oacc[dblk] = mfma16(va, pb, oacc[dblk]);
      }
    }
  };

  stage(0, 0);
  __syncthreads();                   // vmcnt drain + barrier
  int cur = 0;

  for (int t = 0; t < nA; ++t) {
    bool actB = (t < nB);
    if (t + 1 < nA) stage(t + 1, cur ^ 1);   // async prefetch next tile

    // V fragments for this tile (shared by A and B subtiles)
    u32x4 vf[8];
#pragma unroll
    for (int s2 = 0; s2 < 2; ++s2)
#pragma unroll
      for (int dblk = 0; dblk < 4; ++dblk) {
        int R = dblk * 16 + l15;
        const char* vb = (const char*)&Vlds[cur][0] + R * 128 + ((g & 1) << 3);
        int c0 = ((s2 << 2) + (g >> 1)) ^ (R & 7);
        int c1 = ((s2 << 2) + 2 + (g >> 1)) ^ (R & 7);
        uint2 lo = *(const uint2*)(vb + (c0 << 4));
        uint2 hi = *(const uint2*)(vb + (c1 << 4));
        vf[s2 * 4 + dblk] = u32x4{ lo.x, lo.y, hi.x, hi.y };
      }

    // S^T = K.Q for A (and B), sharing K fragments
    f32x4 sA[4], sB[4];
#pragma unroll
    for (int blk = 0; blk < 4; ++blk) {
      int R = blk * 16 + l15;
      const char* kb = (const char*)&Klds[cur][0] + R * 128;
      bf16x8 k0 = *(const bf16x8*)(kb + (((g)     ^ (R & 7)) << 4));
      bf16x8 k1 = *(const bf16x8*)(kb + (((4 + g) ^ (R & 7)) << 4));
      f32x4 z = { 0.f, 0.f, 0.f, 0.f };
      z = mfma16(k0, qA0, z);
      sA[blk] = mfma16(k1, qA1, z);
      if (actB) {
        f32x4 zb = { 0.f, 0.f, 0.f, 0.f };
        zb = mfma16(k0, qB0, zb);
        sB[blk] = mfma16(k1, qB1, zb);
      }
    }

    if (t == nA - 1) {               // causal mask, final tile of A
      int tk0 = t * 64;
#pragma unroll
      for (int blk = 0; blk < 4; ++blk)
#pragma unroll
        for (int j = 0; j < 4; ++j) {
          int tk = tk0 + blk * 16 + 4 * g + j;
          if (tk > qaA) sA[blk][j] = -1e30f;
        }
    }
    smpv(sA, mA, lAs, oA, vf);

    if (actB) {
      if (t == nB - 1) {
        int tk0 = t * 64;
#pragma unroll
        for (int blk = 0; blk < 4; ++blk)
#pragma unroll
          for (int j = 0; j < 4; ++j) {
            int tk = tk0 + blk * 16 + 4 * g + j;
            if (tk > qaB) sB[blk][j] = -1e30f;
          }
      }
      smpv(sB, mB, lBs, oB, vf);
    }

    __syncthreads();                 // all waves done with buf cur; next staged
    cur ^= 1;
  }

  float invA = 1.0f / lAs;
  u16* orA = AO + ((size_t)b * 2048 + q0A + l15) * 1024 + h * 64 + 4 * g;
#pragma unroll
  for (int dblk = 0; dblk < 4; ++dblk) {
    u32x2 o = { pk2(oA[dblk][0] * invA, oA[dblk][1] * invA),
                pk2(oA[dblk][2] * invA, oA[dblk][3] * invA) };
    *(u32x2*)(orA + dblk * 16) = o;
  }
  float invB = 1.0f / lBs;
  u16* orB = AO + ((size_t)b * 2048 + q0B + l15) * 1024 + h * 64 + 4 * g;
#pragma unroll
  for (int dblk = 0; dblk < 4; ++dblk) {
    u32x2 o = { pk2(oB[dblk][0] * invB, oB[dblk][1] * invB),
                pk2(oB[dblk][2] * invB, oB[dblk][3] * invB) };
    *(u32x2*)(orB + dblk * 16) = o;
  }
}

// ---- launcher ---------------------------------------------------------------
extern "C" void kernel_launch(void* const* d_in, const int* in_sizes, int n_in,
                              void* d_out, int out_size, void* d_ws, size_t ws_size,
                              hipStream_t stream) {
  (void)in_sizes; (void)n_in; (void)out_size; (void)ws_size;
  const float* x     = (const float*)d_in[0];
  const float* Wqkv  = (const float*)d_in[1];
  const float* bqkv  = (const float*)d_in[2];
  const float* Wproj = (const float*)d_in[3];
  const float* bproj = (const float*)d_in[4];
  const int*   pos   = (const int*)d_in[5];

  char* ws = (char*)d_ws;
  u16*   XB     = (u16*)(ws + 0);
  u16*   WQKVT  = (u16*)(ws + 8388608);
  u16*   WPROJT = (u16*)(ws + 14680064);
  u16*   QKV    = (u16*)(ws + 16777216);
  u16*   QR     = (u16*)(ws + 41943040);
  u16*   KR     = (u16*)(ws + 50331648);
  u16*   VT     = (u16*)(ws + 58720256);
  u16*   AO     = (u16*)(ws + 67108864);
  float* SIN    = (float*)(ws + 75497472);
  float* COS    = (float*)(ws + 75759616);

  k_cvt_bf16<<<2048, 256, 0, stream>>>(x, XB);
  k_transpose_cvt<<<32 * 96, 256, 0, stream>>>(Wqkv, WQKVT, 3072);
  k_transpose_cvt<<<32 * 32, 256, 0, stream>>>(Wproj, WPROJT, 1024);
  k_tables<<<256, 256, 0, stream>>>(pos, SIN, COS);
  k_gemm<3072, false><<<32 * 24, 256, 0, stream>>>(XB, WQKVT, bqkv, QKV);
  k_rope<<<32 * 32, 256, 0, stream>>>(QKV, SIN, COS, QR, KR, VT);
  k_attn<<<512, 256, 0, stream>>>(QR, KR, VT, AO);
  k_gemm<1024, true><<<32 * 8, 256, 0, stream>>>(AO, WPROJT, bproj, d_out);
}

// Round 4
// 125.406 us; speedup vs baseline: 4.1390x; 1.1301x over previous
//
#include <hip/hip_runtime.h>
#include <hip/hip_bf16.h>
#include <stdint.h>

#define DEV __device__ __forceinline__

typedef unsigned short u16;
typedef unsigned int   u32;
typedef __attribute__((ext_vector_type(8))) short bf16x8;   // 8 bf16 = 4 VGPRs
typedef __attribute__((ext_vector_type(4))) float f32x4;
typedef __attribute__((ext_vector_type(4))) u32   u32x4;
typedef __attribute__((ext_vector_type(2))) u32   u32x2;

// ---- numeric helpers -------------------------------------------------------
DEV u16 f2bf(float f) {            // RNE f32 -> bf16
  u32 u = __builtin_bit_cast(u32, f);
  u = (u + 0x7fffu + ((u >> 16) & 1u)) >> 16;
  return (u16)u;
}
DEV float bf2f(u16 h) { return __builtin_bit_cast(float, (u32)h << 16); }
DEV u32 pk2(float a, float b) {    // pack 2 f32 -> 2 bf16 in one u32 (RNE)
  u32 x = __builtin_bit_cast(u32, a), y = __builtin_bit_cast(u32, b);
  x = (x + 0x7fffu + ((x >> 16) & 1u)) >> 16;
  y = (y + 0x7fffu + ((y >> 16) & 1u)) >> 16;
  return x | (y << 16);
}
DEV u32 cvtpk(float lo, float hi) {  // 1-instr RNE pack (same semantics as pk2)
  u32 r;
  asm("v_cvt_pk_bf16_f32 %0, %1, %2" : "=v"(r) : "v"(lo), "v"(hi));
  return r;
}
DEV f32x4 mfma16(bf16x8 a, bf16x8 b, f32x4 c) {
  return __builtin_amdgcn_mfma_f32_16x16x32_bf16(a, b, c, 0, 0, 0);
}
DEV void gload16(const void* g, void* l) {   // global -> LDS direct, 16B/lane
  __builtin_amdgcn_global_load_lds(
      (const __attribute__((address_space(1))) void*)g,
      (__attribute__((address_space(3))) void*)l, 16, 0, 0);
}

// ---- problem constants -----------------------------------------------------
// B=2 T=2048 DIM=1024 HEADS=16 HEAD_DIM=64; tokens = 4096
// workspace layout (bytes):
//  XB      0         x as bf16            [4096][1024]
//  WQKVT   8388608   Wqkv^T bf16          [3072][1024]
//  WPROJT  14680064  Wproj^T bf16         [1024][1024]
//  QKV     16777216  qkv bf16             [4096][3072]
//  QR      41943040  roped*scale Q bf16   [32][2048][64]
//  KR      50331648  roped K bf16         [32][2048][64]
//  VT      58720256  V^T bf16             [32][64][2048]
//  AO      67108864  attn out bf16        [4096][1024]
//  SIN     75497472  f32 [2048][32]
//  COS     75759616  f32 [2048][32]

// ---- prep kernels ----------------------------------------------------------
__global__ __launch_bounds__(256) void k_cvt_bf16(const float* __restrict__ in,
                                                  u16* __restrict__ out) {
  size_t i = ((size_t)blockIdx.x * 256 + threadIdx.x) * 8;
  float4 a = *(const float4*)(in + i);
  float4 b = *(const float4*)(in + i + 4);
  u32x4 o = { pk2(a.x, a.y), pk2(a.z, a.w), pk2(b.x, b.y), pk2(b.z, b.w) };
  *(u32x4*)(out + i) = o;
}

// W [1024][Ndim] f32 -> WT [Ndim][1024] bf16 (coalesced both sides via LDS)
__global__ __launch_bounds__(256) void k_transpose_cvt(const float* __restrict__ W,
                                                       u16* __restrict__ WT,
                                                       int Ndim) {
  int bk = blockIdx.x & 31;        // K/32 = 32
  int bn = blockIdx.x >> 5;
  int k0 = bk * 32, n0 = bn * 32;
  __shared__ float t[32][33];
  int tx = threadIdx.x & 31, ty = threadIdx.x >> 5; // ty 0..7
#pragma unroll
  for (int i = 0; i < 4; ++i)
    t[ty + 8 * i][tx] = W[(size_t)(k0 + ty + 8 * i) * Ndim + n0 + tx];
  __syncthreads();
#pragma unroll
  for (int i = 0; i < 4; ++i) {
    int n = ty + 8 * i;
    WT[(size_t)(n0 + n) * 1024 + k0 + tx] = f2bf(t[tx][n]);
  }
}

__global__ __launch_bounds__(256) void k_tables(const int* __restrict__ posp,
                                                float* __restrict__ sint,
                                                float* __restrict__ cost) {
  int i = blockIdx.x * 256 + threadIdx.x;   // 65536 = 2048*32
  int t = i >> 5, d = i & 31;
  float theta = exp2f(-(float)d * (13.2877123795494f / 32.0f));
  float ang = (float)(posp[0] + t) * theta;
  sint[i] = sinf(ang);
  cost[i] = cosf(ang);
}

// ---- GEMM: C[4096][N] = A[4096][1024] @ BT^T + bias ------------------------
// 128x128 tile, BK=32, 4 waves (2x2 of 64x64), mfma 16x16x32 bf16.
// Staging: global_load_lds width=16, linear LDS dest, swizzle applied on the
// GLOBAL source address (rule #21). Reads use the same XOR chunk swizzle.
template <int N, bool OUTF32>
__global__ __launch_bounds__(256, 2) void k_gemm(const u16* __restrict__ A,
                                                 const u16* __restrict__ BT,
                                                 const float* __restrict__ bias,
                                                 void* __restrict__ Cout) {
  constexpr int K = 1024;
  int bm = blockIdx.x & 31;             // M/128 = 32
  int bn = blockIdx.x >> 5;
  int m0 = bm * 128, n0 = bn * 128;
  int tid = threadIdx.x, lane = tid & 63, w = tid >> 6;
  int g = lane >> 4, l15 = lane & 15;
  int wr = w >> 1, wc = w & 1;

  __shared__ u16 Alds[128 * 32];
  __shared__ u16 Blds[128 * 32];

  f32x4 acc[4][4] = {};

  int rowW = w * 16 + (lane >> 2);
  int cSrc = (lane & 3) ^ ((lane >> 3) & 3);
  const u16* Ag0 = A  + (size_t)(m0 + rowW) * K + cSrc * 8;
  const u16* Ag1 = A  + (size_t)(m0 + 64 + rowW) * K + cSrc * 8;
  const u16* Bg0 = BT + (size_t)(n0 + rowW) * K + cSrc * 8;
  const u16* Bg1 = BT + (size_t)(n0 + 64 + rowW) * K + cSrc * 8;
  char* AldsW0 = (char*)Alds + w * 1024;          // + lane*16 by HW
  char* AldsW1 = (char*)Alds + 4096 + w * 1024;
  char* BldsW0 = (char*)Blds + w * 1024;
  char* BldsW1 = (char*)Blds + 4096 + w * 1024;

  for (int k0 = 0; k0 < K; k0 += 32) {
    gload16(Ag0 + k0, AldsW0);
    gload16(Ag1 + k0, AldsW1);
    gload16(Bg0 + k0, BldsW0);
    gload16(Bg1 + k0, BldsW1);
    __syncthreads();                    // drains vmcnt (compiler-inserted)
    bf16x8 af[4], bf_[4];
#pragma unroll
    for (int m = 0; m < 4; ++m) {
      int r = wr * 64 + m * 16 + l15;
      af[m] = *(const bf16x8*)((const char*)Alds + r * 64 + ((g ^ ((r >> 1) & 3)) << 4));
    }
#pragma unroll
    for (int n = 0; n < 4; ++n) {
      int r = wc * 64 + n * 16 + l15;
      bf_[n] = *(const bf16x8*)((const char*)Blds + r * 64 + ((g ^ ((r >> 1) & 3)) << 4));
    }
#pragma unroll
    for (int m = 0; m < 4; ++m)
#pragma unroll
      for (int n = 0; n < 4; ++n)
        acc[m][n] = mfma16(af[m], bf_[n], acc[m][n]);
    __syncthreads();
  }

#pragma unroll
  for (int m = 0; m < 4; ++m) {
    int rowb = m0 + wr * 64 + m * 16 + 4 * g;
#pragma unroll
    for (int n = 0; n < 4; ++n) {
      int col = n0 + wc * 64 + n * 16 + l15;
      float bv = bias[col];
#pragma unroll
      for (int j = 0; j < 4; ++j) {
        float v = acc[m][n][j] + bv;
        if constexpr (OUTF32)
          ((float*)Cout)[(size_t)(rowb + j) * N + col] = v;
        else
          ((u16*)Cout)[(size_t)(rowb + j) * N + col] = f2bf(v);
      }
    }
  }
}

// ---- RoPE + head reshape + V transpose -------------------------------------
__global__ __launch_bounds__(256) void k_rope(const u16* __restrict__ qkv,
                                              const float* __restrict__ sint,
                                              const float* __restrict__ cost,
                                              u16* __restrict__ QR,
                                              u16* __restrict__ KR,
                                              u16* __restrict__ VT) {
  int bid = blockIdx.x;
  int bh = bid >> 5;                 // T/64 = 32 blocks per (b,h)
  int t0 = (bid & 31) * 64;
  int b = bh >> 4, h = bh & 15;
  int tid = threadIdx.x;

  int dp = tid & 31;
  int tt0 = tid >> 5;                 // 0..7
#pragma unroll
  for (int r = 0; r < 8; ++r) {
    int tl = r * 8 + tt0;
    int t = t0 + tl;
    int tok = b * 2048 + t;
    const u16* row = qkv + (size_t)tok * 3072;
    float sn = sint[t * 32 + dp], cs = cost[t * 32 + dp];

    u32 qq = *(const u32*)(row + h * 64 + 2 * dp);
    float x1 = bf2f((u16)qq), x2 = bf2f((u16)(qq >> 16));
    u16* qo = QR + ((size_t)bh * 2048 + t) * 64;
    qo[dp]      = f2bf(0.125f * (x1 * cs - x2 * sn));
    qo[dp + 32] = f2bf(0.125f * (x1 * sn + x2 * cs));

    u32 kk = *(const u32*)(row + 1024 + h * 64 + 2 * dp);
    x1 = bf2f((u16)kk); x2 = bf2f((u16)(kk >> 16));
    u16* ko = KR + ((size_t)bh * 2048 + t) * 64;
    ko[dp]      = f2bf(x1 * cs - x2 * sn);
    ko[dp + 32] = f2bf(x1 * sn + x2 * cs);
  }

  __shared__ u16 vld[64][72];
#pragma unroll
  for (int it = 0; it < 2; ++it) {
    int slot = it * 256 + tid;
    int tl = slot >> 3, ch = slot & 7;
    int tok = b * 2048 + t0 + tl;
    uint4 v = *(const uint4*)(qkv + (size_t)tok * 3072 + 2048 + h * 64 + ch * 8);
    *(uint4*)&vld[tl][ch * 8] = v;
  }
  __syncthreads();
#pragma unroll
  for (int it = 0; it < 2; ++it) {
    int slot = it * 256 + tid;
    int d = slot >> 3, tch = slot & 7;
    u16 tmp[8];
#pragma unroll
    for (int i = 0; i < 8; ++i) tmp[i] = vld[tch * 8 + i][d];
    u32x4 o = { (u32)tmp[0] | ((u32)tmp[1] << 16), (u32)tmp[2] | ((u32)tmp[3] << 16),
                (u32)tmp[4] | ((u32)tmp[5] << 16), (u32)tmp[6] | ((u32)tmp[7] << 16) };
    *(u32x4*)(VT + ((size_t)bh * 64 + d) * 2048 + t0 + tch * 8) = o;
  }
}

// ---- causal flash attention v2 ----------------------------------------------
// Pair-balanced 64-row q-tiles (tA=31-i, tB=i), KVBLK=128 (two 64-key halves
// per barrier), LDS dbuf via global_load_lds with source-side XOR swizzle.
// Register-pressure-aware: V frags loaded inside PV loop, A/B strictly
// sequential, defer-max rescale (T13), 1-instr cvt_pk packing, per-lane
// partial l (no psum shuffles), setprio around MFMA clusters (T5).
__global__ __launch_bounds__(256, 2) void k_attn(const u16* __restrict__ QR,
                                                 const u16* __restrict__ KR,
                                                 const u16* __restrict__ VT,
                                                 u16* __restrict__ AO) {
  int tid = threadIdx.x;
  int w = tid >> 6, lane = tid & 63;
  int g = lane >> 4, l15 = lane & 15;
  int l7 = l15 & 7, g2 = g >> 1;

  int x = blockIdx.x & 7;            // XCD slot
  int i = blockIdx.x >> 3;           // 0..63
  int bh = x + 8 * (i >> 4);         // 4 bh per XCD slot -> L2 locality
  int pi = i & 15;                   // pair 0..15
  int tA = 31 - pi, tB = pi;         // 64-row q-tile indices
  int nhA = tA + 1, nhB = tB + 1;    // 64-key halves; nhA >= 17 > nhB
  int NT = (nhA + 1) >> 1;           // 128-key staged tiles
  int b = bh >> 4, h = bh & 15;
  int q0A = tA * 64 + w * 16;
  int q0B = tB * 64 + w * 16;
  int qaA = q0A + l15, qaB = q0B + l15;

  const u16* Kg = KR + (size_t)bh * 2048 * 64;
  const u16* Vg = VT + (size_t)bh * 64 * 2048;

  __shared__ u16 Klds[2][128 * 64];  // 16KB per buf: [key][64 d], swizzled
  __shared__ u16 Vlds[2][64 * 128];  // 16KB per buf: [d][128 key], swizzled

  const u16* QrA = QR + ((size_t)bh * 2048 + q0A + l15) * 64 + 8 * g;
  bf16x8 qA0 = *(const bf16x8*)(QrA);
  bf16x8 qA1 = *(const bf16x8*)(QrA + 32);
  const u16* QrB = QR + ((size_t)bh * 2048 + q0B + l15) * 64 + 8 * g;
  bf16x8 qB0 = *(const bf16x8*)(QrB);
  bf16x8 qB1 = *(const bf16x8*)(QrB + 32);

  f32x4 oA[4] = {}, oB[4] = {};
  float mA = -1e30f, lA = 0.f, mB = -1e30f, lB = 0.f;

  // hoisted LDS read constants
  int kx0 = ((g ^ l7) << 4);                 // K frag chunk offsets (bytes)
  int kx1 = (((4 + g) ^ l7) << 4);
  int vbase = l15 * 256 + ((g & 1) << 3);    // V row base (bytes)

  // staging: wave w covers K rows [w*32, w*32+32), V rows [w*16, w*16+16)
  int kR = lane >> 3;                        // 0..7
  int kSw = (lane & 7) ^ kR;                 // K source chunk
  int vR = lane >> 4;                        // 0..3
  const char *Kb, *Vb;

  auto stage = [&](int kt, int buf) {
    const u16* kg = Kg + ((size_t)(kt * 128 + w * 32 + kR)) * 64 + kSw * 8;
    u16* kld = &Klds[buf][(w * 32) * 64];
#pragma unroll
    for (int j = 0; j < 4; ++j)
      gload16(kg + j * 8 * 64, kld + j * 8 * 64);
#pragma unroll
    for (int j = 0; j < 4; ++j) {
      int sc = (lane & 15) ^ ((j & 1) * 4 + vR);
      gload16(Vg + (size_t)(w * 16 + j * 4 + vR) * 2048 + kt * 128 + sc * 8,
              &Vlds[buf][(w * 16 + j * 4) * 128]);
    }
  };

  // softmax + PV for one 16q x 64k subtile; h = key half (compile-time)
  auto smpv = [&](f32x4 (&sb)[4], int h, float& m, float& l, f32x4 (&o)[4]) {
    float mx = fmaxf(fmaxf(fmaxf(sb[0][0], sb[0][1]), fmaxf(sb[0][2], sb[0][3])),
                     fmaxf(fmaxf(sb[1][0], sb[1][1]), fmaxf(sb[1][2], sb[1][3])));
    mx = fmaxf(mx, fmaxf(fmaxf(fmaxf(sb[2][0], sb[2][1]), fmaxf(sb[2][2], sb[2][3])),
                         fmaxf(fmaxf(sb[3][0], sb[3][1]), fmaxf(sb[3][2], sb[3][3]))));
    mx = fmaxf(mx, __shfl_xor(mx, 16));
    mx = fmaxf(mx, __shfl_xor(mx, 32));
    if (!__all(mx <= m + 8.0f)) {          // defer-max: rescale only when needed
      float mnew = fmaxf(m, mx);
      float a = __builtin_amdgcn_exp2f((m - mnew) * 1.44269504f);
      l *= a;
#pragma unroll
      for (int d = 0; d < 4; ++d) o[d] *= a;
      m = mnew;
    }
    float em = m * 1.44269504f;
    float p[4][4];
    float ps = 0.f;
#pragma unroll
    for (int blk = 0; blk < 4; ++blk)
#pragma unroll
      for (int j = 0; j < 4; ++j) {
        float pv = __builtin_amdgcn_exp2f(__builtin_fmaf(sb[blk][j], 1.44269504f, -em));
        p[blk][j] = pv;
        ps += pv;
      }
    l += ps;                                // per-lane partial; reduced at end
    __builtin_amdgcn_s_setprio(1);
#pragma unroll
    for (int s2 = 0; s2 < 2; ++s2) {
      u32x4 pw = { cvtpk(p[2 * s2][0], p[2 * s2][1]),
                   cvtpk(p[2 * s2][2], p[2 * s2][3]),
                   cvtpk(p[2 * s2 + 1][0], p[2 * s2 + 1][1]),
                   cvtpk(p[2 * s2 + 1][2], p[2 * s2 + 1][3]) };
      bf16x8 pb = __builtin_bit_cast(bf16x8, pw);
      int cl = ((8 * h + 4 * s2 + g2) ^ l7) << 4;
      int ch = ((8 * h + 4 * s2 + 2 + g2) ^ l7) << 4;
#pragma unroll
      for (int dblk = 0; dblk < 4; ++dblk) {
        uint2 lo = *(const uint2*)(Vb + vbase + dblk * 4096 + cl);
        uint2 hi = *(const uint2*)(Vb + vbase + dblk * 4096 + ch);
        bf16x8 va = __builtin_bit_cast(bf16x8, u32x4{ lo.x, lo.y, hi.x, hi.y });
        o[dblk] = mfma16(va, pb, o[dblk]);
      }
    }
    __builtin_amdgcn_s_setprio(0);
  };

  stage(0, 0);
  __syncthreads();
  int cur = 0;

  for (int t = 0; t < NT; ++t) {
    if (t + 1 < NT) stage(t + 1, cur ^ 1);   // async prefetch next 128-key tile
    Kb = (const char*)&Klds[cur][0];
    Vb = (const char*)&Vlds[cur][0];
#pragma unroll
    for (int h = 0; h < 2; ++h) {
      int hidx = 2 * t + h;
      if (hidx >= nhA) continue;             // uniform per block
      bool actB = hidx < nhB;
      // K fragments for this 64-key half
      bf16x8 kf0[4], kf1[4];
#pragma unroll
      for (int blk = 0; blk < 4; ++blk) {
        const char* kb = Kb + h * 8192 + blk * 2048 + l15 * 128;
        kf0[blk] = *(const bf16x8*)(kb + kx0);
        kf1[blk] = *(const bf16x8*)(kb + kx1);
      }
      f32x4 sA[4], sB[4];
      __builtin_amdgcn_s_setprio(1);
#pragma unroll
      for (int blk = 0; blk < 4; ++blk) {
        f32x4 z = { 0.f, 0.f, 0.f, 0.f };
        z = mfma16(kf0[blk], qA0, z);
        sA[blk] = mfma16(kf1[blk], qA1, z);
      }
      if (actB) {
#pragma unroll
        for (int blk = 0; blk < 4; ++blk) {
          f32x4 z = { 0.f, 0.f, 0.f, 0.f };
          z = mfma16(kf0[blk], qB0, z);
          sB[blk] = mfma16(kf1[blk], qB1, z);
        }
      }
      __builtin_amdgcn_s_setprio(0);

      if (hidx == nhA - 1) {                 // causal mask, final half of A
        int tk0 = hidx * 64;
#pragma unroll
        for (int blk = 0; blk < 4; ++blk)
#pragma unroll
          for (int j = 0; j < 4; ++j) {
            int tk = tk0 + blk * 16 + 4 * g + j;
            if (tk > qaA) sA[blk][j] = -1e30f;
          }
      }
      smpv(sA, h, mA, lA, oA);

      if (actB) {
        if (hidx == nhB - 1) {
          int tk0 = hidx * 64;
#pragma unroll
          for (int blk = 0; blk < 4; ++blk)
#pragma unroll
            for (int j = 0; j < 4; ++j) {
              int tk = tk0 + blk * 16 + 4 * g + j;
              if (tk > qaB) sB[blk][j] = -1e30f;
            }
        }
        smpv(sB, h, mB, lB, oB);
      }
    }
    __syncthreads();
    cur ^= 1;
  }

  float ltA = lA + __shfl_xor(lA, 16);
  ltA += __shfl_xor(ltA, 32);
  float invA = 1.0f / ltA;
  u16* orA = AO + ((size_t)b * 2048 + q0A + l15) * 1024 + h * 64 + 4 * g;
#pragma unroll
  for (int dblk = 0; dblk < 4; ++dblk) {
    u32x2 o = { cvtpk(oA[dblk][0] * invA, oA[dblk][1] * invA),
                cvtpk(oA[dblk][2] * invA, oA[dblk][3] * invA) };
    *(u32x2*)(orA + dblk * 16) = o;
  }
  float ltB = lB + __shfl_xor(lB, 16);
  ltB += __shfl_xor(ltB, 32);
  float invB = 1.0f / ltB;
  u16* orB = AO + ((size_t)b * 2048 + q0B + l15) * 1024 + h * 64 + 4 * g;
#pragma unroll
  for (int dblk = 0; dblk < 4; ++dblk) {
    u32x2 o = { cvtpk(oB[dblk][0] * invB, oB[dblk][1] * invB),
                cvtpk(oB[dblk][2] * invB, oB[dblk][3] * invB) };
    *(u32x2*)(orB + dblk * 16) = o;
  }
}

// ---- launcher ---------------------------------------------------------------
extern "C" void kernel_launch(void* const* d_in, const int* in_sizes, int n_in,
                              void* d_out, int out_size, void* d_ws, size_t ws_size,
                              hipStream_t stream) {
  (void)in_sizes; (void)n_in; (void)out_size; (void)ws_size;
  const float* x     = (const float*)d_in[0];
  const float* Wqkv  = (const float*)d_in[1];
  const float* bqkv  = (const float*)d_in[2];
  const float* Wproj = (const float*)d_in[3];
  const float* bproj = (const float*)d_in[4];
  const int*   pos   = (const int*)d_in[5];

  char* ws = (char*)d_ws;
  u16*   XB     = (u16*)(ws + 0);
  u16*   WQKVT  = (u16*)(ws + 8388608);
  u16*   WPROJT = (u16*)(ws + 14680064);
  u16*   QKV    = (u16*)(ws + 16777216);
  u16*   QR     = (u16*)(ws + 41943040);
  u16*   KR     = (u16*)(ws + 50331648);
  u16*   VT     = (u16*)(ws + 58720256);
  u16*   AO     = (u16*)(ws + 67108864);
  float* SIN    = (float*)(ws + 75497472);
  float* COS    = (float*)(ws + 75759616);

  k_cvt_bf16<<<2048, 256, 0, stream>>>(x, XB);
  k_transpose_cvt<<<32 * 96, 256, 0, stream>>>(Wqkv, WQKVT, 3072);
  k_transpose_cvt<<<32 * 32, 256, 0, stream>>>(Wproj, WPROJT, 1024);
  k_tables<<<256, 256, 0, stream>>>(pos, SIN, COS);
  k_gemm<3072, false><<<32 * 24, 256, 0, stream>>>(XB, WQKVT, bqkv, QKV);
  k_rope<<<32 * 32, 256, 0, stream>>>(QKV, SIN, COS, QR, KR, VT);
  k_attn<<<512, 256, 0, stream>>>(QR, KR, VT, AO);
  k_gemm<1024, true><<<32 * 8, 256, 0, stream>>>(AO, WPROJT, bproj, d_out);
}

// Round 5
// 124.708 us; speedup vs baseline: 4.1622x; 1.0056x over previous
//
#include <hip/hip_runtime.h>
#include <hip/hip_bf16.h>
#include <stdint.h>

#define DEV __device__ __forceinline__

typedef unsigned short u16;
typedef unsigned int   u32;
typedef __attribute__((ext_vector_type(8))) short bf16x8;   // 8 bf16 = 4 VGPRs
typedef __attribute__((ext_vector_type(4))) float f32x4;
typedef __attribute__((ext_vector_type(4))) u32   u32x4;
typedef __attribute__((ext_vector_type(2))) u32   u32x2;

// ---- numeric helpers -------------------------------------------------------
DEV u16 f2bf(float f) {            // RNE f32 -> bf16
  u32 u = __builtin_bit_cast(u32, f);
  u = (u + 0x7fffu + ((u >> 16) & 1u)) >> 16;
  return (u16)u;
}
DEV float bf2f(u16 h) { return __builtin_bit_cast(float, (u32)h << 16); }
DEV u32 pk2(float a, float b) {    // pack 2 f32 -> 2 bf16 in one u32 (RNE)
  u32 x = __builtin_bit_cast(u32, a), y = __builtin_bit_cast(u32, b);
  x = (x + 0x7fffu + ((x >> 16) & 1u)) >> 16;
  y = (y + 0x7fffu + ((y >> 16) & 1u)) >> 16;
  return x | (y << 16);
}
DEV u32 cvtpk(float lo, float hi) {  // 1-instr RNE pack (same semantics as pk2)
  u32 r;
  asm("v_cvt_pk_bf16_f32 %0, %1, %2" : "=v"(r) : "v"(lo), "v"(hi));
  return r;
}
DEV f32x4 mfma16(bf16x8 a, bf16x8 b, f32x4 c) {
  return __builtin_amdgcn_mfma_f32_16x16x32_bf16(a, b, c, 0, 0, 0);
}
DEV void gload16(const void* g, void* l) {   // global -> LDS direct, 16B/lane
  __builtin_amdgcn_global_load_lds(
      (const __attribute__((address_space(1))) void*)g,
      (__attribute__((address_space(3))) void*)l, 16, 0, 0);
}

// ---- problem constants -----------------------------------------------------
// B=2 T=2048 DIM=1024 HEADS=16 HEAD_DIM=64; tokens = 4096
// workspace layout (bytes):
//  XB      0         x as bf16            [4096][1024]
//  WQKVT   8388608   Wqkv^T bf16          [3072][1024]
//  WPROJT  14680064  Wproj^T bf16         [1024][1024]
//  QKV     16777216  qkv bf16             [4096][3072]
//  QR      41943040  roped*scale Q bf16   [32][2048][64]
//  KR      50331648  roped K bf16         [32][2048][64]
//  VT      58720256  V^T bf16             [32][64][2048]
//  AO      67108864  attn out bf16        [4096][1024]
//  SIN     75497472  f32 [2048][32]
//  COS     75759616  f32 [2048][32]

// ---- prep kernels ----------------------------------------------------------
__global__ __launch_bounds__(256) void k_cvt_bf16(const float* __restrict__ in,
                                                  u16* __restrict__ out) {
  size_t i = ((size_t)blockIdx.x * 256 + threadIdx.x) * 8;
  float4 a = *(const float4*)(in + i);
  float4 b = *(const float4*)(in + i + 4);
  u32x4 o = { pk2(a.x, a.y), pk2(a.z, a.w), pk2(b.x, b.y), pk2(b.z, b.w) };
  *(u32x4*)(out + i) = o;
}

// W [1024][Ndim] f32 -> WT [Ndim][1024] bf16 (coalesced both sides via LDS)
__global__ __launch_bounds__(256) void k_transpose_cvt(const float* __restrict__ W,
                                                       u16* __restrict__ WT,
                                                       int Ndim) {
  int bk = blockIdx.x & 31;        // K/32 = 32
  int bn = blockIdx.x >> 5;
  int k0 = bk * 32, n0 = bn * 32;
  __shared__ float t[32][33];
  int tx = threadIdx.x & 31, ty = threadIdx.x >> 5; // ty 0..7
#pragma unroll
  for (int i = 0; i < 4; ++i)
    t[ty + 8 * i][tx] = W[(size_t)(k0 + ty + 8 * i) * Ndim + n0 + tx];
  __syncthreads();
#pragma unroll
  for (int i = 0; i < 4; ++i) {
    int n = ty + 8 * i;
    WT[(size_t)(n0 + n) * 1024 + k0 + tx] = f2bf(t[tx][n]);
  }
}

__global__ __launch_bounds__(256) void k_tables(const int* __restrict__ posp,
                                                float* __restrict__ sint,
                                                float* __restrict__ cost) {
  int i = blockIdx.x * 256 + threadIdx.x;   // 65536 = 2048*32
  int t = i >> 5, d = i & 31;
  float theta = exp2f(-(float)d * (13.2877123795494f / 32.0f));
  float ang = (float)(posp[0] + t) * theta;
  sint[i] = sinf(ang);
  cost[i] = cosf(ang);
}

// ---- GEMM: C[4096][N] = A[4096][1024] @ BT^T + bias ------------------------
// 128x128 tile, BK=32, 4 waves (2x2 of 64x64), mfma 16x16x32 bf16.
// Staging: global_load_lds width=16, linear LDS dest, swizzle applied on the
// GLOBAL source address (rule #21). Reads use the same XOR chunk swizzle.
template <int N, bool OUTF32>
__global__ __launch_bounds__(256, 2) void k_gemm(const u16* __restrict__ A,
                                                 const u16* __restrict__ BT,
                                                 const float* __restrict__ bias,
                                                 void* __restrict__ Cout) {
  constexpr int K = 1024;
  int bm = blockIdx.x & 31;             // M/128 = 32
  int bn = blockIdx.x >> 5;
  int m0 = bm * 128, n0 = bn * 128;
  int tid = threadIdx.x, lane = tid & 63, w = tid >> 6;
  int g = lane >> 4, l15 = lane & 15;
  int wr = w >> 1, wc = w & 1;

  __shared__ u16 Alds[128 * 32];
  __shared__ u16 Blds[128 * 32];

  f32x4 acc[4][4] = {};

  int rowW = w * 16 + (lane >> 2);
  int cSrc = (lane & 3) ^ ((lane >> 3) & 3);
  const u16* Ag0 = A  + (size_t)(m0 + rowW) * K + cSrc * 8;
  const u16* Ag1 = A  + (size_t)(m0 + 64 + rowW) * K + cSrc * 8;
  const u16* Bg0 = BT + (size_t)(n0 + rowW) * K + cSrc * 8;
  const u16* Bg1 = BT + (size_t)(n0 + 64 + rowW) * K + cSrc * 8;
  char* AldsW0 = (char*)Alds + w * 1024;          // + lane*16 by HW
  char* AldsW1 = (char*)Alds + 4096 + w * 1024;
  char* BldsW0 = (char*)Blds + w * 1024;
  char* BldsW1 = (char*)Blds + 4096 + w * 1024;

  for (int k0 = 0; k0 < K; k0 += 32) {
    gload16(Ag0 + k0, AldsW0);
    gload16(Ag1 + k0, AldsW1);
    gload16(Bg0 + k0, BldsW0);
    gload16(Bg1 + k0, BldsW1);
    __syncthreads();                    // drains vmcnt (compiler-inserted)
    bf16x8 af[4], bf_[4];
#pragma unroll
    for (int m = 0; m < 4; ++m) {
      int r = wr * 64 + m * 16 + l15;
      af[m] = *(const bf16x8*)((const char*)Alds + r * 64 + ((g ^ ((r >> 1) & 3)) << 4));
    }
#pragma unroll
    for (int n = 0; n < 4; ++n) {
      int r = wc * 64 + n * 16 + l15;
      bf_[n] = *(const bf16x8*)((const char*)Blds + r * 64 + ((g ^ ((r >> 1) & 3)) << 4));
    }
#pragma unroll
    for (int m = 0; m < 4; ++m)
#pragma unroll
      for (int n = 0; n < 4; ++n)
        acc[m][n] = mfma16(af[m], bf_[n], acc[m][n]);
    __syncthreads();
  }

#pragma unroll
  for (int m = 0; m < 4; ++m) {
    int rowb = m0 + wr * 64 + m * 16 + 4 * g;
#pragma unroll
    for (int n = 0; n < 4; ++n) {
      int col = n0 + wc * 64 + n * 16 + l15;
      float bv = bias[col];
#pragma unroll
      for (int j = 0; j < 4; ++j) {
        float v = acc[m][n][j] + bv;
        if constexpr (OUTF32)
          ((float*)Cout)[(size_t)(rowb + j) * N + col] = v;
        else
          ((u16*)Cout)[(size_t)(rowb + j) * N + col] = f2bf(v);
      }
    }
  }
}

// ---- RoPE + head reshape + V transpose -------------------------------------
__global__ __launch_bounds__(256) void k_rope(const u16* __restrict__ qkv,
                                              const float* __restrict__ sint,
                                              const float* __restrict__ cost,
                                              u16* __restrict__ QR,
                                              u16* __restrict__ KR,
                                              u16* __restrict__ VT) {
  int bid = blockIdx.x;
  int bh = bid >> 5;                 // T/64 = 32 blocks per (b,h)
  int t0 = (bid & 31) * 64;
  int b = bh >> 4, h = bh & 15;
  int tid = threadIdx.x;

  int dp = tid & 31;
  int tt0 = tid >> 5;                 // 0..7
#pragma unroll
  for (int r = 0; r < 8; ++r) {
    int tl = r * 8 + tt0;
    int t = t0 + tl;
    int tok = b * 2048 + t;
    const u16* row = qkv + (size_t)tok * 3072;
    float sn = sint[t * 32 + dp], cs = cost[t * 32 + dp];

    u32 qq = *(const u32*)(row + h * 64 + 2 * dp);
    float x1 = bf2f((u16)qq), x2 = bf2f((u16)(qq >> 16));
    u16* qo = QR + ((size_t)bh * 2048 + t) * 64;
    qo[dp]      = f2bf(0.125f * (x1 * cs - x2 * sn));
    qo[dp + 32] = f2bf(0.125f * (x1 * sn + x2 * cs));

    u32 kk = *(const u32*)(row + 1024 + h * 64 + 2 * dp);
    x1 = bf2f((u16)kk); x2 = bf2f((u16)(kk >> 16));
    u16* ko = KR + ((size_t)bh * 2048 + t) * 64;
    ko[dp]      = f2bf(x1 * cs - x2 * sn);
    ko[dp + 32] = f2bf(x1 * sn + x2 * cs);
  }

  __shared__ u16 vld[64][72];
#pragma unroll
  for (int it = 0; it < 2; ++it) {
    int slot = it * 256 + tid;
    int tl = slot >> 3, ch = slot & 7;
    int tok = b * 2048 + t0 + tl;
    uint4 v = *(const uint4*)(qkv + (size_t)tok * 3072 + 2048 + h * 64 + ch * 8);
    *(uint4*)&vld[tl][ch * 8] = v;
  }
  __syncthreads();
#pragma unroll
  for (int it = 0; it < 2; ++it) {
    int slot = it * 256 + tid;
    int d = slot >> 3, tch = slot & 7;
    u16 tmp[8];
#pragma unroll
    for (int i = 0; i < 8; ++i) tmp[i] = vld[tch * 8 + i][d];
    u32x4 o = { (u32)tmp[0] | ((u32)tmp[1] << 16), (u32)tmp[2] | ((u32)tmp[3] << 16),
                (u32)tmp[4] | ((u32)tmp[5] << 16), (u32)tmp[6] | ((u32)tmp[7] << 16) };
    *(u32x4*)(VT + ((size_t)bh * 64 + d) * 2048 + t0 + tch * 8) = o;
  }
}

// ---- causal flash attention v3: single-tile blocks, 4 blocks/CU ------------
// 1024 blocks = 32 bh x 32 q-tiles (64 rows); 4 waves, one 16-row subtile per
// wave. KVBLK=64 double-buffered LDS (32KB) staged via global_load_lds with
// source-side XOR swizzle. Heavy-first dispatch (t descending with blockIdx)
// + near-full residency (4 blocks/CU) gives causal load balance. defer-max
// (T13), cvt_pk pack, per-lane partial l, setprio (T5).
__global__ __launch_bounds__(256, 4) void k_attn(const u16* __restrict__ QR,
                                                 const u16* __restrict__ KR,
                                                 const u16* __restrict__ VT,
                                                 u16* __restrict__ AO) {
  int tid = threadIdx.x;
  int w = tid >> 6, lane = tid & 63;
  int g = lane >> 4, l15 = lane & 15;
  int l7 = l15 & 7, g2 = g >> 1;

  int idx = blockIdx.x;
  int tt = 31 - (idx >> 5);          // q-tile 31..0 (heavy first)
  int bh = idx & 31;                 // bh mod 8 = XCD slot -> 4 bh per XCD
  int nt = tt + 1;                   // 64-key tiles to process
  int b = bh >> 4, h = bh & 15;
  int q0 = tt * 64 + w * 16;         // wave's 16-row subtile
  int qa = q0 + l15;

  const u16* Kg = KR + (size_t)bh * 2048 * 64;
  const u16* Vg = VT + (size_t)bh * 64 * 2048;

  __shared__ u16 Klds[2][64 * 64];   // 8KB/buf: [key][64 d], swizzled
  __shared__ u16 Vlds[2][64 * 64];   // 8KB/buf: [d][64 key], swizzled

  const u16* Qr = QR + ((size_t)bh * 2048 + q0 + l15) * 64 + 8 * g;
  bf16x8 qf0 = *(const bf16x8*)(Qr);
  bf16x8 qf1 = *(const bf16x8*)(Qr + 32);

  f32x4 o[4] = {};
  float m = -1e30f, l = 0.f;

  // hoisted LDS read constants
  int kx0 = ((g ^ l7) << 4);                 // K frag chunk offsets (bytes)
  int kx1 = (((4 + g) ^ l7) << 4);
  int vx0 = ((g2 ^ l7) << 4);                // V chunks s2=0: {g2, 2+g2}
  int vx1 = (((2 + g2) ^ l7) << 4);
  int vx2 = (((4 + g2) ^ l7) << 4);          // s2=1: {4+g2, 6+g2}
  int vx3 = (((6 + g2) ^ l7) << 4);
  int vbase = l15 * 128 + ((g & 1) << 3);

  // staging: 256 threads cover 64 rows x 8 chunks in 2 issues (K and V each)
  int rstg = lane >> 3;                      // 0..7
  int cswz = (lane & 7) ^ rstg;              // pre-swizzled source chunk

  auto stage = [&](int kt, int buf) {
#pragma unroll
    for (int j = 0; j < 2; ++j) {
      int r = j * 32 + w * 8 + rstg;
      gload16(Kg + (size_t)(kt * 64 + r) * 64 + cswz * 8,
              &Klds[buf][(j * 32 + w * 8) * 64]);
      gload16(Vg + (size_t)r * 2048 + kt * 64 + cswz * 8,
              &Vlds[buf][(j * 32 + w * 8) * 64]);
    }
  };

  stage(0, 0);
  __syncthreads();
  int cur = 0;

  for (int t = 0; t < nt; ++t) {
    if (t + 1 < nt) stage(t + 1, cur ^ 1);   // async prefetch next tile
    const char* Kb = (const char*)&Klds[cur][0];
    const char* Vb = (const char*)&Vlds[cur][0];

    // S^T = K.Q (64 keys x 16 q)
    f32x4 sb[4];
    __builtin_amdgcn_s_setprio(1);
#pragma unroll
    for (int blk = 0; blk < 4; ++blk) {
      const char* kb = Kb + blk * 2048 + l15 * 128;
      bf16x8 k0 = *(const bf16x8*)(kb + kx0);
      bf16x8 k1 = *(const bf16x8*)(kb + kx1);
      f32x4 z = { 0.f, 0.f, 0.f, 0.f };
      z = mfma16(k0, qf0, z);
      sb[blk] = mfma16(k1, qf1, z);
    }
    __builtin_amdgcn_s_setprio(0);

    if (t == nt - 1) {               // causal mask, final tile only
      int tk0 = t * 64;
#pragma unroll
      for (int blk = 0; blk < 4; ++blk)
#pragma unroll
        for (int j = 0; j < 4; ++j) {
          int tk = tk0 + blk * 16 + 4 * g + j;
          if (tk > qa) sb[blk][j] = -1e30f;
        }
    }

    // online softmax (defer-max) + PV
    float mx = fmaxf(fmaxf(fmaxf(sb[0][0], sb[0][1]), fmaxf(sb[0][2], sb[0][3])),
                     fmaxf(fmaxf(sb[1][0], sb[1][1]), fmaxf(sb[1][2], sb[1][3])));
    mx = fmaxf(mx, fmaxf(fmaxf(fmaxf(sb[2][0], sb[2][1]), fmaxf(sb[2][2], sb[2][3])),
                         fmaxf(fmaxf(sb[3][0], sb[3][1]), fmaxf(sb[3][2], sb[3][3]))));
    mx = fmaxf(mx, __shfl_xor(mx, 16));
    mx = fmaxf(mx, __shfl_xor(mx, 32));
    if (!__all(mx <= m + 8.0f)) {
      float mnew = fmaxf(m, mx);
      float a = __builtin_amdgcn_exp2f((m - mnew) * 1.44269504f);
      l *= a;
#pragma unroll
      for (int d = 0; d < 4; ++d) o[d] *= a;
      m = mnew;
    }
    float em = m * 1.44269504f;
    float p[4][4];
    float ps = 0.f;
#pragma unroll
    for (int blk = 0; blk < 4; ++blk)
#pragma unroll
      for (int j = 0; j < 4; ++j) {
        float pv = __builtin_amdgcn_exp2f(__builtin_fmaf(sb[blk][j], 1.44269504f, -em));
        p[blk][j] = pv;
        ps += pv;
      }
    l += ps;

    __builtin_amdgcn_s_setprio(1);
#pragma unroll
    for (int s2 = 0; s2 < 2; ++s2) {
      u32x4 pw = { cvtpk(p[2 * s2][0], p[2 * s2][1]),
                   cvtpk(p[2 * s2][2], p[2 * s2][3]),
                   cvtpk(p[2 * s2 + 1][0], p[2 * s2 + 1][1]),
                   cvtpk(p[2 * s2 + 1][2], p[2 * s2 + 1][3]) };
      bf16x8 pb = __builtin_bit_cast(bf16x8, pw);
      int cl = s2 ? vx2 : vx0;
      int ch = s2 ? vx3 : vx1;
#pragma unroll
      for (int dblk = 0; dblk < 4; ++dblk) {
        uint2 lo = *(const uint2*)(Vb + vbase + dblk * 2048 + cl);
        uint2 hi = *(const uint2*)(Vb + vbase + dblk * 2048 + ch);
        bf16x8 va = __builtin_bit_cast(bf16x8, u32x4{ lo.x, lo.y, hi.x, hi.y });
        o[dblk] = mfma16(va, pb, o[dblk]);
      }
    }
    __builtin_amdgcn_s_setprio(0);

    __syncthreads();
    cur ^= 1;
  }

  float lt = l + __shfl_xor(l, 16);
  lt += __shfl_xor(lt, 32);
  float inv = 1.0f / lt;
  u16* orow = AO + ((size_t)b * 2048 + q0 + l15) * 1024 + h * 64 + 4 * g;
#pragma unroll
  for (int dblk = 0; dblk < 4; ++dblk) {
    u32x2 ov = { cvtpk(o[dblk][0] * inv, o[dblk][1] * inv),
                 cvtpk(o[dblk][2] * inv, o[dblk][3] * inv) };
    *(u32x2*)(orow + dblk * 16) = ov;
  }
}

// ---- launcher ---------------------------------------------------------------
extern "C" void kernel_launch(void* const* d_in, const int* in_sizes, int n_in,
                              void* d_out, int out_size, void* d_ws, size_t ws_size,
                              hipStream_t stream) {
  (void)in_sizes; (void)n_in; (void)out_size; (void)ws_size;
  const float* x     = (const float*)d_in[0];
  const float* Wqkv  = (const float*)d_in[1];
  const float* bqkv  = (const float*)d_in[2];
  const float* Wproj = (const float*)d_in[3];
  const float* bproj = (const float*)d_in[4];
  const int*   pos   = (const int*)d_in[5];

  char* ws = (char*)d_ws;
  u16*   XB     = (u16*)(ws + 0);
  u16*   WQKVT  = (u16*)(ws + 8388608);
  u16*   WPROJT = (u16*)(ws + 14680064);
  u16*   QKV    = (u16*)(ws + 16777216);
  u16*   QR     = (u16*)(ws + 41943040);
  u16*   KR     = (u16*)(ws + 50331648);
  u16*   VT     = (u16*)(ws + 58720256);
  u16*   AO     = (u16*)(ws + 67108864);
  float* SIN    = (float*)(ws + 75497472);
  float* COS    = (float*)(ws + 75759616);

  k_cvt_bf16<<<2048, 256, 0, stream>>>(x, XB);
  k_transpose_cvt<<<32 * 96, 256, 0, stream>>>(Wqkv, WQKVT, 3072);
  k_transpose_cvt<<<32 * 32, 256, 0, stream>>>(Wproj, WPROJT, 1024);
  k_tables<<<256, 256, 0, stream>>>(pos, SIN, COS);
  k_gemm<3072, false><<<32 * 24, 256, 0, stream>>>(XB, WQKVT, bqkv, QKV);
  k_rope<<<32 * 32, 256, 0, stream>>>(QKV, SIN, COS, QR, KR, VT);
  k_attn<<<1024, 256, 0, stream>>>(QR, KR, VT, AO);
  k_gemm<1024, true><<<32 * 8, 256, 0, stream>>>(AO, WPROJT, bproj, d_out);
}